// Round 2
// baseline (11384.038 us; speedup 1.0000x reference)
//
#include <hip/hip_runtime.h>
#include <cstdint>
#include <cstddef>

#define D_MODEL 1024
#define D_STATE 16
#define D_CONVK 4
#define D_INNER 2048
#define DT_RANK 64
#define XDBL_N  (DT_RANK + 2*D_STATE)   // 96
#define BATCH   4
#define SEQL    2048
#define BL      (BATCH*SEQL)            // 8192

// ---------------------------------------------------------------- LayerNorm
__global__ __launch_bounds__(256) void ln_kernel(
    const float* __restrict__ x, const float* __restrict__ g,
    const float* __restrict__ be, float* __restrict__ xn)
{
    int r = blockIdx.x;
    int tid = threadIdx.x;                       // 256 threads, 4 floats each
    const float4 v = reinterpret_cast<const float4*>(x + (size_t)r * D_MODEL)[tid];
    float s  = v.x + v.y + v.z + v.w;
    float ss = v.x*v.x + v.y*v.y + v.z*v.z + v.w*v.w;
    #pragma unroll
    for (int o = 32; o >= 1; o >>= 1) { s += __shfl_down(s, o); ss += __shfl_down(ss, o); }
    __shared__ float sbuf[4], ssbuf[4];
    __shared__ float mu_s, rs_s;
    int wave = tid >> 6, lane = tid & 63;
    if (lane == 0) { sbuf[wave] = s; ssbuf[wave] = ss; }
    __syncthreads();
    if (tid == 0) {
        float S = 0.f, SS = 0.f;
        #pragma unroll
        for (int i = 0; i < 4; ++i) { S += sbuf[i]; SS += ssbuf[i]; }
        float mu = S * (1.0f / D_MODEL);
        float var = SS * (1.0f / D_MODEL) - mu * mu;
        mu_s = mu; rs_s = rsqrtf(var + 1e-5f);
    }
    __syncthreads();
    float mu = mu_s, rs = rs_s;
    const float4 gv = reinterpret_cast<const float4*>(g)[tid];
    const float4 bv = reinterpret_cast<const float4*>(be)[tid];
    float4 o;
    o.x = (v.x - mu) * rs * gv.x + bv.x;
    o.y = (v.y - mu) * rs * gv.y + bv.y;
    o.z = (v.z - mu) * rs * gv.z + bv.z;
    o.w = (v.w - mu) * rs * gv.w + bv.w;
    reinterpret_cast<float4*>(xn + (size_t)r * D_MODEL)[tid] = o;
}

// ------------------------------------------------------------ generic GEMM
// C[r, coloff+c] = sum_k A[r', k] * W[c, k]   (W row-major (N,K))
// flipA: read A row time-flipped within each SEQL segment; flipC: store flipped.
// epi: 0 = plain, 1 = softplus(acc + bias[c]), 2 = acc + bias[c] + resid[r*N+c]
__global__ __launch_bounds__(256) void gemm_kernel(
    const float* __restrict__ A, int lda, int flipA,
    const float* __restrict__ W, int K, int N,
    float* __restrict__ C, int ldc, int coloff, int flipC,
    int epi, const float* __restrict__ bias, const float* __restrict__ resid)
{
    __shared__ float As[16][68];
    __shared__ float Ws[16][68];
    int tid = threadIdx.x;
    int bm = blockIdx.y * 64;
    int bn = blockIdx.x * 64;
    int tx = tid & 15, ty = tid >> 4;
    float acc[4][4] = {};

    for (int k0 = 0; k0 < K; k0 += 16) {
        #pragma unroll
        for (int p = 0; p < 4; ++p) {
            int li = tid + p * 256;
            int m = li >> 4, k = li & 15;
            int gr = bm + m;
            if (flipA) { int t = gr & (SEQL - 1); gr = (gr - t) + (SEQL - 1 - t); }
            As[k][m] = A[(size_t)gr * lda + (k0 + k)];
            int gn = bn + m;
            float wv = 0.f;
            if (gn < N) wv = W[(size_t)gn * K + (k0 + k)];
            Ws[k][m] = wv;
        }
        __syncthreads();
        #pragma unroll
        for (int kk = 0; kk < 16; ++kk) {
            const float4 av = *reinterpret_cast<const float4*>(&As[kk][ty * 4]);
            const float4 wv = *reinterpret_cast<const float4*>(&Ws[kk][tx * 4]);
            float a[4] = {av.x, av.y, av.z, av.w};
            float w[4] = {wv.x, wv.y, wv.z, wv.w};
            #pragma unroll
            for (int i = 0; i < 4; ++i)
                #pragma unroll
                for (int j = 0; j < 4; ++j)
                    acc[i][j] += a[i] * w[j];
        }
        __syncthreads();
    }

    #pragma unroll
    for (int i = 0; i < 4; ++i) {
        int r = bm + ty * 4 + i;
        int rsrow = r;
        if (flipC) { int t = r & (SEQL - 1); rsrow = (r - t) + (SEQL - 1 - t); }
        #pragma unroll
        for (int j = 0; j < 4; ++j) {
            int c = bn + tx * 4 + j;
            if (c >= N) continue;
            float v = acc[i][j];
            if (epi == 1) {
                v += bias[c];
                v = (v > 20.f) ? v : log1pf(expf(v));
            } else if (epi == 2) {
                v += bias[c] + resid[(size_t)r * N + c];
            }
            C[(size_t)rsrow * ldc + coloff + c] = v;
        }
    }
}

// --------------------------------------------- depthwise causal conv + SiLU
__global__ __launch_bounds__(256) void conv_silu_kernel(
    const float* __restrict__ xz, const float* __restrict__ w,
    const float* __restrict__ cb, float* __restrict__ u)
{
    int idx = blockIdx.x * 256 + threadIdx.x;     // R*D_INNER threads
    int d = idx & (D_INNER - 1);
    int r = idx >> 11;                            // chunk-local row
    int t = r & (SEQL - 1);
    int rb = r - t;
    float acc = cb[d];
    #pragma unroll
    for (int j = 0; j < D_CONVK; ++j) {
        int tt = t - (D_CONVK - 1) + j;
        if (tt >= 0)
            acc += w[d * D_CONVK + j] * xz[(size_t)(rb + tt) * (2 * D_INNER) + d];
    }
    float sig = 1.f / (1.f + expf(-acc));
    u[(size_t)r * D_INNER + d] = acc * sig;
}

// ----------------------------------------------------------- selective scan
// 16 lanes per channel. Writes gated output IN PLACE over delta.
__global__ __launch_bounds__(256) void scan_kernel(
    const float* __restrict__ u, const float* deltabuf /* aliases ybuf */,
    const float* __restrict__ xdbl, const float* __restrict__ A_log,
    const float* __restrict__ Dsk, const float* __restrict__ xz,
    float* ybuf /* aliases deltabuf */)
{
    int tid = threadIdx.x;
    int s = tid & 15;
    int cg = tid >> 4;                 // 16 channels per block
    int blk = blockIdx.x;              // CB*128 blocks
    int bb = blk >> 7;                 // chunk-local batch
    int dg = blk & 127;
    int d = dg * 16 + cg;
    const float Av = -expf(A_log[d * D_STATE + s]);
    const float Dv = Dsk[d];
    float h = 0.f;
    const size_t rowbase = (size_t)bb * SEQL;

    for (int t0 = 0; t0 < SEQL; t0 += 8) {
        float dd[8];
        #pragma unroll
        for (int j = 0; j < 8; ++j)
            dd[j] = deltabuf[(rowbase + t0 + j) * D_INNER + d];
        #pragma unroll
        for (int j = 0; j < 8; ++j) {
            size_t r = rowbase + t0 + j;
            float dv = dd[j];
            float uv = u[r * D_INNER + d];
            float Bv = xdbl[r * XDBL_N + DT_RANK + s];
            float Cv = xdbl[r * XDBL_N + DT_RANK + D_STATE + s];
            float dA = expf(dv * Av);
            h = dA * h + (dv * uv) * Bv;
            float y = h * Cv;
            y += __shfl_xor(y, 1);
            y += __shfl_xor(y, 2);
            y += __shfl_xor(y, 4);
            y += __shfl_xor(y, 8);
            if (s == 0) {
                float zv = xz[r * (2 * D_INNER) + D_INNER + d];
                float sig = 1.f / (1.f + expf(-zv));
                ybuf[r * D_INNER + d] = (y + uv * Dv) * (zv * sig);
            }
        }
    }
}

// ------------------------------------------------------------------- launch
extern "C" void kernel_launch(void* const* d_in, const int* in_sizes, int n_in,
                              void* d_out, int out_size, void* d_ws, size_t ws_size,
                              hipStream_t stream)
{
    const float* x      = (const float*)d_in[0];
    const float* gamma  = (const float*)d_in[1];
    const float* beta   = (const float*)d_in[2];
    const float* in_w[2]   = {(const float*)d_in[3],  (const float*)d_in[12]};
    const float* conv_w[2] = {(const float*)d_in[4],  (const float*)d_in[13]};
    const float* conv_b[2] = {(const float*)d_in[5],  (const float*)d_in[14]};
    const float* xp_w[2]   = {(const float*)d_in[6],  (const float*)d_in[15]};
    const float* dtp_w[2]  = {(const float*)d_in[7],  (const float*)d_in[16]};
    const float* dtp_b[2]  = {(const float*)d_in[8],  (const float*)d_in[17]};
    const float* A_log[2]  = {(const float*)d_in[9],  (const float*)d_in[18]};
    const float* Dsk[2]    = {(const float*)d_in[10], (const float*)d_in[19]};
    const float* out_w[2]  = {(const float*)d_in[11], (const float*)d_in[20]};
    const float* proj_w = (const float*)d_in[21];
    const float* proj_b = (const float*)d_in[22];
    float* out = (float*)d_out;

    // ---- pick batches-per-chunk so the workspace fits ws_size ----
    // floats needed per chunk of R=CB*SEQL rows:
    //   xn R*1024 | xz R*4096 | u R*2048 | xdbl R*96 | delta R*2048 | cat R*2048
    int CB = BATCH;
    while (CB > 1) {
        size_t R = (size_t)CB * SEQL;
        size_t fl = R * (1024 + 4096 + 2048 + 96 + 2048 + 2048);
        if (fl * sizeof(float) <= ws_size) break;
        CB >>= 1;
    }
    const int NC = BATCH / CB;
    const size_t R = (size_t)CB * SEQL;

    float* ws    = (float*)d_ws;
    float* xn    = ws;                         // R*1024
    float* xz    = xn    + R * 1024;           // R*4096
    float* u     = xz    + R * 4096;           // R*2048
    float* xdbl  = u     + R * 2048;           // R*96
    float* delta = xdbl  + R * 96;             // R*2048 (scan writes y in place)
    float* cat   = delta + R * 2048;           // R*2048

    for (int c = 0; c < NC; ++c) {
        const size_t row0 = (size_t)c * R;

        ln_kernel<<<(int)R, 256, 0, stream>>>(x + row0 * D_MODEL, gamma, beta, xn);

        for (int dir = 0; dir < 2; ++dir) {
            // in-proj: xz = xn(flip?) @ in_w.T   M=R K=1024 N=4096
            dim3 g1(2 * D_INNER / 64, (unsigned)(R / 64));
            gemm_kernel<<<g1, 256, 0, stream>>>(xn, D_MODEL, dir,
                                                in_w[dir], D_MODEL, 2 * D_INNER,
                                                xz, 2 * D_INNER, 0, 0,
                                                0, nullptr, nullptr);
            // depthwise conv + silu -> u
            conv_silu_kernel<<<(int)(R * D_INNER / 256), 256, 0, stream>>>(
                xz, conv_w[dir], conv_b[dir], u);
            // x_dbl = u @ xp_w.T   M=R K=2048 N=96
            dim3 g2(2, (unsigned)(R / 64));
            gemm_kernel<<<g2, 256, 0, stream>>>(u, D_INNER, 0,
                                                xp_w[dir], D_INNER, XDBL_N,
                                                xdbl, XDBL_N, 0, 0,
                                                0, nullptr, nullptr);
            // delta = softplus(dt @ dtp_w.T + dtp_b)  M=R K=64 N=2048
            dim3 g3(D_INNER / 64, (unsigned)(R / 64));
            gemm_kernel<<<g3, 256, 0, stream>>>(xdbl, XDBL_N, 0,
                                                dtp_w[dir], DT_RANK, D_INNER,
                                                delta, D_INNER, 0, 0,
                                                1, dtp_b[dir], nullptr);
            // selective scan + D-skip + silu(z) gating (in place into delta)
            scan_kernel<<<CB * 128, 256, 0, stream>>>(u, delta, xdbl, A_log[dir],
                                                      Dsk[dir], xz, delta);
            // out-proj into concat buffer: M=R K=2048 N=1024
            dim3 g4(D_MODEL / 64, (unsigned)(R / 64));
            gemm_kernel<<<g4, 256, 0, stream>>>(delta, D_INNER, 0,
                                                out_w[dir], D_INNER, D_MODEL,
                                                cat, 2 * D_MODEL, dir ? D_MODEL : 0, dir,
                                                0, nullptr, nullptr);
        }
        // final: out = x + cat @ proj_w.T + proj_b   M=R K=2048 N=1024
        dim3 g5(D_MODEL / 64, (unsigned)(R / 64));
        gemm_kernel<<<g5, 256, 0, stream>>>(cat, 2 * D_MODEL, 0,
                                            proj_w, 2 * D_MODEL, D_MODEL,
                                            out + row0 * D_MODEL, D_MODEL, 0, 0,
                                            2, proj_b, x + row0 * D_MODEL);
    }
}

// Round 3
// 6257.177 us; speedup vs baseline: 1.8194x; 1.8194x over previous
//
#include <hip/hip_runtime.h>
#include <cstdint>
#include <cstddef>

#define D_MODEL 1024
#define D_STATE 16
#define D_CONVK 4
#define D_INNER 2048
#define DT_RANK 64
#define XDBL_N  (DT_RANK + 2*D_STATE)   // 96
#define BATCH   4
#define SEQL    2048
#define SSEG    32                      // time segments for parallel scan
#define TSEG    (SEQL/SSEG)             // 64

// ---------------------------------------------------------------- LayerNorm
__global__ __launch_bounds__(256) void ln_kernel(
    const float* __restrict__ x, const float* __restrict__ g,
    const float* __restrict__ be, float* __restrict__ xn)
{
    int r = blockIdx.x;
    int tid = threadIdx.x;                       // 256 threads, 4 floats each
    const float4 v = reinterpret_cast<const float4*>(x + (size_t)r * D_MODEL)[tid];
    float s  = v.x + v.y + v.z + v.w;
    float ss = v.x*v.x + v.y*v.y + v.z*v.z + v.w*v.w;
    #pragma unroll
    for (int o = 32; o >= 1; o >>= 1) { s += __shfl_down(s, o); ss += __shfl_down(ss, o); }
    __shared__ float sbuf[4], ssbuf[4];
    __shared__ float mu_s, rs_s;
    int wave = tid >> 6, lane = tid & 63;
    if (lane == 0) { sbuf[wave] = s; ssbuf[wave] = ss; }
    __syncthreads();
    if (tid == 0) {
        float S = 0.f, SS = 0.f;
        #pragma unroll
        for (int i = 0; i < 4; ++i) { S += sbuf[i]; SS += ssbuf[i]; }
        float mu = S * (1.0f / D_MODEL);
        float var = SS * (1.0f / D_MODEL) - mu * mu;
        mu_s = mu; rs_s = rsqrtf(var + 1e-5f);
    }
    __syncthreads();
    float mu = mu_s, rs = rs_s;
    const float4 gv = reinterpret_cast<const float4*>(g)[tid];
    const float4 bv = reinterpret_cast<const float4*>(be)[tid];
    float4 o;
    o.x = (v.x - mu) * rs * gv.x + bv.x;
    o.y = (v.y - mu) * rs * gv.y + bv.y;
    o.z = (v.z - mu) * rs * gv.z + bv.z;
    o.w = (v.w - mu) * rs * gv.w + bv.w;
    reinterpret_cast<float4*>(xn + (size_t)r * D_MODEL)[tid] = o;
}

// ------------------------------------------------------------ generic GEMM
// C[r, coloff+c] = sum_k A[r', k] * op(W)[c, k]
//   wtrans=0: W row-major (N,K): W[c*K+k].  wtrans=1: W row-major (K,N): W[k*N+c].
// flipA: read A row time-flipped within each SEQL segment; flipC: store flipped.
// epi: 0 plain | 1 softplus(acc+bias[c]) | 2 acc+bias[c]+resid[r*N+c] | 3 C += acc
__global__ __launch_bounds__(256) void gemm_kernel(
    const float* __restrict__ A, int lda, int flipA,
    const float* __restrict__ W, int K, int N, int wtrans,
    float* __restrict__ C, int ldc, int coloff, int flipC,
    int epi, const float* __restrict__ bias, const float* __restrict__ resid)
{
    __shared__ float As[16][68];
    __shared__ float Ws[16][68];
    int tid = threadIdx.x;
    int bm = blockIdx.y * 64;
    int bn = blockIdx.x * 64;
    int tx = tid & 15, ty = tid >> 4;
    float acc[4][4] = {};

    for (int k0 = 0; k0 < K; k0 += 16) {
        #pragma unroll
        for (int p = 0; p < 4; ++p) {
            int li = tid + p * 256;
            int m = li >> 4, k = li & 15;
            int gr = bm + m;
            if (flipA) { int t = gr & (SEQL - 1); gr = (gr - t) + (SEQL - 1 - t); }
            As[k][m] = A[(size_t)gr * lda + (k0 + k)];
            if (!wtrans) {
                int gn = bn + m;
                float wv = 0.f;
                if (gn < N) wv = W[(size_t)gn * K + (k0 + k)];
                Ws[k][m] = wv;
            } else {
                int kt = li >> 6, mt = li & 63;     // coalesced over N
                int gn = bn + mt;
                float wv = 0.f;
                if (gn < N) wv = W[(size_t)(k0 + kt) * N + gn];
                Ws[kt][mt] = wv;
            }
        }
        __syncthreads();
        #pragma unroll
        for (int kk = 0; kk < 16; ++kk) {
            const float4 av = *reinterpret_cast<const float4*>(&As[kk][ty * 4]);
            const float4 wv = *reinterpret_cast<const float4*>(&Ws[kk][tx * 4]);
            float a[4] = {av.x, av.y, av.z, av.w};
            float w[4] = {wv.x, wv.y, wv.z, wv.w};
            #pragma unroll
            for (int i = 0; i < 4; ++i)
                #pragma unroll
                for (int j = 0; j < 4; ++j)
                    acc[i][j] += a[i] * w[j];
        }
        __syncthreads();
    }

    #pragma unroll
    for (int i = 0; i < 4; ++i) {
        int r = bm + ty * 4 + i;
        int rsrow = r;
        if (flipC) { int t = r & (SEQL - 1); rsrow = (r - t) + (SEQL - 1 - t); }
        #pragma unroll
        for (int j = 0; j < 4; ++j) {
            int c = bn + tx * 4 + j;
            if (c >= N) continue;
            float v = acc[i][j];
            if (epi == 1) {
                v += bias[c];
                v = (v > 20.f) ? v : log1pf(expf(v));
            } else if (epi == 2) {
                v += bias[c] + resid[(size_t)r * N + c];
            }
            size_t oidx = (size_t)rsrow * ldc + coloff + c;
            if (epi == 3) C[oidx] += v; else C[oidx] = v;
        }
    }
}

// --------------------------------------------- depthwise causal conv + SiLU
__global__ __launch_bounds__(256) void conv_silu_kernel(
    const float* __restrict__ xz, const float* __restrict__ w,
    const float* __restrict__ cb, float* __restrict__ u)
{
    int idx = blockIdx.x * 256 + threadIdx.x;     // R*D_INNER threads
    int d = idx & (D_INNER - 1);
    int r = idx >> 11;                            // chunk-local row
    int t = r & (SEQL - 1);
    int rb = r - t;
    float acc = cb[d];
    #pragma unroll
    for (int j = 0; j < D_CONVK; ++j) {
        int tt = t - (D_CONVK - 1) + j;
        if (tt >= 0)
            acc += w[d * D_CONVK + j] * xz[(size_t)(rb + tt) * (2 * D_INNER) + d];
    }
    float sig = 1.f / (1.f + __expf(-acc));
    u[(size_t)r * D_INNER + d] = acc * sig;
}

// -------------------------------------------- selective scan, segment pass 1
// Per segment: local scan with h_in=0. Emits P = prod(dA) and local h_end,
// laid out [(b*SSEG+g)*D_INNER + d]*16 + s.
__global__ __launch_bounds__(256) void scan1_kernel(
    const float* __restrict__ u, const float* __restrict__ delta,
    const float* __restrict__ xdbl, const float* __restrict__ A_log,
    float* __restrict__ Pbuf, float* __restrict__ Hbuf)
{
    int tid = threadIdx.x;
    int s = tid & 15, cg = tid >> 4;
    int blk = blockIdx.x;                  // ((bb*SSEG)+g)*128 + dg
    int dg = blk & 127;
    int g  = (blk >> 7) & (SSEG - 1);
    int bb = blk >> 12;
    int d = dg * 16 + cg;
    const float Av = -expf(A_log[d * D_STATE + s]);
    float h = 0.f, P = 1.f;
    const size_t r0 = (size_t)bb * SEQL + (size_t)g * TSEG;

    for (int t0 = 0; t0 < TSEG; t0 += 8) {
        float dd[8], uu[8], Bv[8];
        #pragma unroll
        for (int j = 0; j < 8; ++j) dd[j] = delta[(r0 + t0 + j) * D_INNER + d];
        #pragma unroll
        for (int j = 0; j < 8; ++j) uu[j] = u[(r0 + t0 + j) * D_INNER + d];
        #pragma unroll
        for (int j = 0; j < 8; ++j) Bv[j] = xdbl[(r0 + t0 + j) * XDBL_N + DT_RANK + s];
        #pragma unroll
        for (int j = 0; j < 8; ++j) {
            float dA = __expf(dd[j] * Av);
            h = dA * h + (dd[j] * uu[j]) * Bv[j];
            P *= dA;
        }
    }
    size_t o = (((size_t)bb * SSEG + g) * D_INNER + d) * D_STATE + s;
    Pbuf[o] = P;
    Hbuf[o] = h;
}

// ------------------------------------- scan fixup: turn (P, h_end) into h_in
__global__ __launch_bounds__(256) void scan_fix_kernel(
    const float* __restrict__ Pbuf, float* __restrict__ Hbuf)
{
    int idx = blockIdx.x * 256 + threadIdx.x;   // CB*D_INNER*D_STATE threads
    int b  = idx >> 15;                         // idx / (2048*16)
    int ds = idx & 32767;
    float hin = 0.f;
    for (int g = 0; g < SSEG; ++g) {
        size_t o = ((size_t)(b * SSEG + g)) * (D_INNER * D_STATE) + ds;
        float he = Hbuf[o];
        float pp = Pbuf[o];
        Hbuf[o] = hin;                          // overwrite with segment h_in
        hin = pp * hin + he;
    }
}

// -------------------------------------------- selective scan, segment pass 2
// Re-run each segment from h_in; y = C·h, + D-skip, × silu(z); write over delta.
__global__ __launch_bounds__(256) void scan2_kernel(
    const float* __restrict__ u, const float* deltabuf /* aliases ybuf */,
    const float* __restrict__ xdbl, const float* __restrict__ Hin,
    const float* __restrict__ A_log, const float* __restrict__ Dsk,
    const float* __restrict__ xz, float* ybuf /* aliases deltabuf */)
{
    int tid = threadIdx.x;
    int s = tid & 15, cg = tid >> 4;
    int blk = blockIdx.x;
    int dg = blk & 127;
    int g  = (blk >> 7) & (SSEG - 1);
    int bb = blk >> 12;
    int d = dg * 16 + cg;
    const float Av = -expf(A_log[d * D_STATE + s]);
    const float Dv = Dsk[d];
    const size_t r0 = (size_t)bb * SEQL + (size_t)g * TSEG;
    float h = Hin[(((size_t)bb * SSEG + g) * D_INNER + d) * D_STATE + s];

    for (int t0 = 0; t0 < TSEG; t0 += 8) {
        float dd[8], uu[8], Bv[8], Cv[8], zz[8];
        #pragma unroll
        for (int j = 0; j < 8; ++j) dd[j] = deltabuf[(r0 + t0 + j) * D_INNER + d];
        #pragma unroll
        for (int j = 0; j < 8; ++j) uu[j] = u[(r0 + t0 + j) * D_INNER + d];
        #pragma unroll
        for (int j = 0; j < 8; ++j) Bv[j] = xdbl[(r0 + t0 + j) * XDBL_N + DT_RANK + s];
        #pragma unroll
        for (int j = 0; j < 8; ++j) Cv[j] = xdbl[(r0 + t0 + j) * XDBL_N + DT_RANK + D_STATE + s];
        if (s == 0) {
            #pragma unroll
            for (int j = 0; j < 8; ++j)
                zz[j] = xz[(r0 + t0 + j) * (2 * D_INNER) + D_INNER + d];
        }
        #pragma unroll
        for (int j = 0; j < 8; ++j) {
            float dA = __expf(dd[j] * Av);
            h = dA * h + (dd[j] * uu[j]) * Bv[j];
            float y = h * Cv[j];
            y += __shfl_xor(y, 1);
            y += __shfl_xor(y, 2);
            y += __shfl_xor(y, 4);
            y += __shfl_xor(y, 8);
            if (s == 0) {
                float zv = zz[j];
                float sig = 1.f / (1.f + __expf(-zv));
                ybuf[(r0 + t0 + j) * D_INNER + d] = (y + uu[j] * Dv) * (zv * sig);
            }
        }
    }
}

// ------------------------------------------------------------------- launch
extern "C" void kernel_launch(void* const* d_in, const int* in_sizes, int n_in,
                              void* d_out, int out_size, void* d_ws, size_t ws_size,
                              hipStream_t stream)
{
    const float* x      = (const float*)d_in[0];
    const float* gamma  = (const float*)d_in[1];
    const float* beta   = (const float*)d_in[2];
    const float* in_w[2]   = {(const float*)d_in[3],  (const float*)d_in[12]};
    const float* conv_w[2] = {(const float*)d_in[4],  (const float*)d_in[13]};
    const float* conv_b[2] = {(const float*)d_in[5],  (const float*)d_in[14]};
    const float* xp_w[2]   = {(const float*)d_in[6],  (const float*)d_in[15]};
    const float* dtp_w[2]  = {(const float*)d_in[7],  (const float*)d_in[16]};
    const float* dtp_b[2]  = {(const float*)d_in[8],  (const float*)d_in[17]};
    const float* A_log[2]  = {(const float*)d_in[9],  (const float*)d_in[18]};
    const float* Dsk[2]    = {(const float*)d_in[10], (const float*)d_in[19]};
    const float* out_w[2]  = {(const float*)d_in[11], (const float*)d_in[20]};
    const float* proj_w = (const float*)d_in[21];
    const float* proj_b = (const float*)d_in[22];
    float* out = (float*)d_out;

    // ---- pick batches-per-chunk so the workspace fits ws_size ----
    // fixed: Wf 2*1024*2048. per chunk of R=CB*SEQL rows:
    //   xn R*1024 | xz R*4096 | u R*2048 | xdbl R*96 | delta R*2048
    //   P,H: 2 * CB*SSEG*D_INNER*D_STATE
    const size_t WF_FL = 2ull * 1024 * 2048;
    int CB = BATCH;
    while (CB > 1) {
        size_t R = (size_t)CB * SEQL;
        size_t fl = WF_FL + R * (1024 + 4096 + 2048 + 96 + 2048)
                  + 2ull * CB * SSEG * D_INNER * D_STATE;
        if (fl * sizeof(float) <= ws_size) break;
        CB >>= 1;
    }
    const int NC = BATCH / CB;
    const size_t R = (size_t)CB * SEQL;

    float* ws    = (float*)d_ws;
    float* Wf    = ws;                         // 2 * 1024*2048 (fused out@proj)
    float* xn    = Wf    + WF_FL;              // R*1024
    float* xz    = xn    + R * 1024;           // R*4096
    float* u     = xz    + R * 4096;           // R*2048
    float* xdbl  = u     + R * 2048;           // R*96
    float* delta = xdbl  + R * 96;             // R*2048 (scan2 writes y in place)
    float* Pbuf  = delta + R * 2048;           // CB*SSEG*2048*16
    float* Hbuf  = Pbuf  + (size_t)CB * SSEG * D_INNER * D_STATE;

    // ---- fuse output weights: Wf[dir][m, d] = sum_m1 proj_w[m, dir*1024+m1] * out_w[m1, d]
    {
        dim3 gf(2048 / 64, 1024 / 64);
        for (int dir = 0; dir < 2; ++dir)
            gemm_kernel<<<gf, 256, 0, stream>>>(proj_w + dir * 1024, 2 * D_MODEL, 0,
                                                out_w[dir], 1024, 2048, 1,
                                                Wf + (size_t)dir * 1024 * 2048, 2048, 0, 0,
                                                0, nullptr, nullptr);
    }

    for (int c = 0; c < NC; ++c) {
        const size_t row0 = (size_t)c * R;

        ln_kernel<<<(int)R, 256, 0, stream>>>(x + row0 * D_MODEL, gamma, beta, xn);

        for (int dir = 0; dir < 2; ++dir) {
            // in-proj: xz = xn(flip?) @ in_w.T   M=R K=1024 N=4096
            dim3 g1(2 * D_INNER / 64, (unsigned)(R / 64));
            gemm_kernel<<<g1, 256, 0, stream>>>(xn, D_MODEL, dir,
                                                in_w[dir], D_MODEL, 2 * D_INNER, 0,
                                                xz, 2 * D_INNER, 0, 0,
                                                0, nullptr, nullptr);
            // depthwise conv + silu -> u
            conv_silu_kernel<<<(int)(R * D_INNER / 256), 256, 0, stream>>>(
                xz, conv_w[dir], conv_b[dir], u);
            // x_dbl = u @ xp_w.T   M=R K=2048 N=96
            dim3 g2(2, (unsigned)(R / 64));
            gemm_kernel<<<g2, 256, 0, stream>>>(u, D_INNER, 0,
                                                xp_w[dir], D_INNER, XDBL_N, 0,
                                                xdbl, XDBL_N, 0, 0,
                                                0, nullptr, nullptr);
            // delta = softplus(dt @ dtp_w.T + dtp_b)  M=R K=64 N=2048
            dim3 g3(D_INNER / 64, (unsigned)(R / 64));
            gemm_kernel<<<g3, 256, 0, stream>>>(xdbl, XDBL_N, 0,
                                                dtp_w[dir], DT_RANK, D_INNER, 0,
                                                delta, D_INNER, 0, 0,
                                                1, dtp_b[dir], nullptr);
            // segment-parallel selective scan (y gated, in place into delta)
            int nblk = CB * SSEG * 128;
            scan1_kernel<<<nblk, 256, 0, stream>>>(u, delta, xdbl, A_log[dir],
                                                   Pbuf, Hbuf);
            scan_fix_kernel<<<CB * 128, 256, 0, stream>>>(Pbuf, Hbuf);
            scan2_kernel<<<nblk, 256, 0, stream>>>(u, delta, xdbl, Hbuf,
                                                   A_log[dir], Dsk[dir], xz, delta);
            // fused out+proj: out(+)= y @ Wf[dir].T  M=R K=2048 N=1024
            dim3 g4(D_MODEL / 64, (unsigned)(R / 64));
            gemm_kernel<<<g4, 256, 0, stream>>>(delta, D_INNER, 0,
                                                Wf + (size_t)dir * 1024 * 2048, D_INNER, D_MODEL, 0,
                                                out + row0 * D_MODEL, D_MODEL, 0, dir,
                                                dir == 0 ? 2 : 3, proj_b,
                                                x + row0 * D_MODEL);
        }
    }
}

// Round 4
// 2779.239 us; speedup vs baseline: 4.0961x; 2.2514x over previous
//
#include <hip/hip_runtime.h>
#include <cstdint>
#include <cstddef>

#define D_MODEL 1024
#define D_STATE 16
#define D_CONVK 4
#define D_INNER 2048
#define DT_RANK 64
#define XDBL_N  (DT_RANK + 2*D_STATE)   // 96
#define BATCH   4
#define SEQL    2048
#define SSEG    32                      // time segments for parallel scan
#define TSEG    (SEQL/SSEG)             // 64

typedef __attribute__((ext_vector_type(4))) float f32x4;
typedef __attribute__((ext_vector_type(8))) short short8v;

__device__ __forceinline__ short f2bf(float f) {
    union { float f; unsigned u; } c; c.f = f;
    unsigned u = c.u;
    return (short)((u + 0x7fffu + ((u >> 16) & 1u)) >> 16);
}

// ---------------------------------------------------------------- LayerNorm
__global__ __launch_bounds__(256) void ln_kernel(
    const float* __restrict__ x, const float* __restrict__ g,
    const float* __restrict__ be, float* __restrict__ xn)
{
    int r = blockIdx.x;
    int tid = threadIdx.x;                       // 256 threads, 4 floats each
    const float4 v = reinterpret_cast<const float4*>(x + (size_t)r * D_MODEL)[tid];
    float s  = v.x + v.y + v.z + v.w;
    float ss = v.x*v.x + v.y*v.y + v.z*v.z + v.w*v.w;
    #pragma unroll
    for (int o = 32; o >= 1; o >>= 1) { s += __shfl_down(s, o); ss += __shfl_down(ss, o); }
    __shared__ float sbuf[4], ssbuf[4];
    __shared__ float mu_s, rs_s;
    int wave = tid >> 6, lane = tid & 63;
    if (lane == 0) { sbuf[wave] = s; ssbuf[wave] = ss; }
    __syncthreads();
    if (tid == 0) {
        float S = 0.f, SS = 0.f;
        #pragma unroll
        for (int i = 0; i < 4; ++i) { S += sbuf[i]; SS += ssbuf[i]; }
        float mu = S * (1.0f / D_MODEL);
        float var = SS * (1.0f / D_MODEL) - mu * mu;
        mu_s = mu; rs_s = rsqrtf(var + 1e-5f);
    }
    __syncthreads();
    float mu = mu_s, rs = rs_s;
    const float4 gv = reinterpret_cast<const float4*>(g)[tid];
    const float4 bv = reinterpret_cast<const float4*>(be)[tid];
    float4 o;
    o.x = (v.x - mu) * rs * gv.x + bv.x;
    o.y = (v.y - mu) * rs * gv.y + bv.y;
    o.z = (v.z - mu) * rs * gv.z + bv.z;
    o.w = (v.w - mu) * rs * gv.w + bv.w;
    reinterpret_cast<float4*>(xn + (size_t)r * D_MODEL)[tid] = o;
}

// --------------------------------------------------- bf16 MFMA GEMM (128x128)
// C[r, coloff+c] = sum_k A[r',k]*W[c,k], fp32 in memory, bf16 MFMA compute.
// A (M,K) lda; W (N,K); requires K % 32 == 0, M % 128 == 0. N arbitrary (guarded).
// flipA/flipC: time-flip row within SEQL segment. epi: 0 plain | 1 softplus+bias
// | 2 +bias+resid | 3 C += acc.
__global__ __launch_bounds__(256) void mgemm_kernel(
    const float* __restrict__ A, int lda, int flipA,
    const float* __restrict__ W, int K, int N,
    float* __restrict__ C, int ldc, int coloff, int flipC,
    int epi, const float* __restrict__ bias, const float* __restrict__ resid)
{
    __shared__ short As[128 * 32];
    __shared__ short Ws[128 * 32];
    const int t = threadIdx.x;
    const int bm = blockIdx.y * 128;
    const int bn = blockIdx.x * 128;

    // staging: thread t handles row srow, k-half shalf (16 fp32)
    const int srow = t >> 1;
    const int shalf = t & 1;
    const int ssw = (srow >> 1) & 3;
    int gr = bm + srow;
    if (flipA) { int tt = gr & (SEQL - 1); gr = gr - tt + (SEQL - 1 - tt); }
    const float* Ap = A + (size_t)gr * lda + 16 * shalf;
    const int gn = bn + srow;
    const bool wvalid = (gn < N);
    const float* Wp = W + (size_t)(wvalid ? gn : 0) * K + 16 * shalf;
    const int ws0 = srow * 32 + (((2 * shalf + 0) ^ ssw) << 3);
    const int ws1 = srow * 32 + (((2 * shalf + 1) ^ ssw) << 3);

    // mfma: wave w owns 64x64 sub-tile at (wr, wc)
    const int w = t >> 6, l = t & 63;
    const int wr = w >> 1, wc = w & 1;
    const int lr = l & 15, ls = l >> 4;
    f32x4 acc[4][4] = {};

    int aoff[4], boff[4];
    #pragma unroll
    for (int i = 0; i < 4; ++i) {
        int ra = wr * 64 + i * 16 + lr;
        aoff[i] = ra * 32 + ((ls ^ ((ra >> 1) & 3)) << 3);
        int rb = wc * 64 + i * 16 + lr;
        boff[i] = rb * 32 + ((ls ^ ((rb >> 1) & 3)) << 3);
    }

    for (int k0 = 0; k0 < K; k0 += 32) {
        {
            const float4* p = (const float4*)(Ap + k0);
            float4 v0 = p[0], v1 = p[1], v2 = p[2], v3 = p[3];
            short8v s0 = { f2bf(v0.x), f2bf(v0.y), f2bf(v0.z), f2bf(v0.w),
                           f2bf(v1.x), f2bf(v1.y), f2bf(v1.z), f2bf(v1.w) };
            short8v s1 = { f2bf(v2.x), f2bf(v2.y), f2bf(v2.z), f2bf(v2.w),
                           f2bf(v3.x), f2bf(v3.y), f2bf(v3.z), f2bf(v3.w) };
            *(short8v*)&As[ws0] = s0;
            *(short8v*)&As[ws1] = s1;
        }
        {
            float4 v0 = {0,0,0,0}, v1 = {0,0,0,0}, v2 = {0,0,0,0}, v3 = {0,0,0,0};
            if (wvalid) {
                const float4* p = (const float4*)(Wp + k0);
                v0 = p[0]; v1 = p[1]; v2 = p[2]; v3 = p[3];
            }
            short8v s0 = { f2bf(v0.x), f2bf(v0.y), f2bf(v0.z), f2bf(v0.w),
                           f2bf(v1.x), f2bf(v1.y), f2bf(v1.z), f2bf(v1.w) };
            short8v s1 = { f2bf(v2.x), f2bf(v2.y), f2bf(v2.z), f2bf(v2.w),
                           f2bf(v3.x), f2bf(v3.y), f2bf(v3.z), f2bf(v3.w) };
            *(short8v*)&Ws[ws0] = s0;
            *(short8v*)&Ws[ws1] = s1;
        }
        __syncthreads();
        short8v af[4], bf[4];
        #pragma unroll
        for (int i = 0; i < 4; ++i) af[i] = *(const short8v*)&As[aoff[i]];
        #pragma unroll
        for (int i = 0; i < 4; ++i) bf[i] = *(const short8v*)&Ws[boff[i]];
        #pragma unroll
        for (int mi = 0; mi < 4; ++mi)
            #pragma unroll
            for (int ni = 0; ni < 4; ++ni)
                acc[mi][ni] = __builtin_amdgcn_mfma_f32_16x16x32_bf16(
                    af[mi], bf[ni], acc[mi][ni], 0, 0, 0);
        __syncthreads();
    }

    #pragma unroll
    for (int mi = 0; mi < 4; ++mi) {
        #pragma unroll
        for (int e = 0; e < 4; ++e) {
            int r = bm + wr * 64 + mi * 16 + ls * 4 + e;
            int rs = r;
            if (flipC) { int tt = r & (SEQL - 1); rs = r - tt + (SEQL - 1 - tt); }
            #pragma unroll
            for (int ni = 0; ni < 4; ++ni) {
                int c = bn + wc * 64 + ni * 16 + lr;
                if (c >= N) continue;
                float v = acc[mi][ni][e];
                if (epi == 1) {
                    v += bias[c];
                    v = (v > 20.f) ? v : log1pf(expf(v));
                } else if (epi == 2) {
                    v += bias[c] + resid[(size_t)r * N + c];
                }
                size_t o = (size_t)rs * ldc + coloff + c;
                if (epi == 3) C[o] += v; else C[o] = v;
            }
        }
    }
}

// ------------------------------------------------------------ fp32 GEMM (Wf)
// Used once for the fused weight product (wtrans=1: W is (K,N) row-major).
__global__ __launch_bounds__(256) void gemm_kernel(
    const float* __restrict__ A, int lda,
    const float* __restrict__ W, int K, int N, int wtrans,
    float* __restrict__ C, int ldc)
{
    __shared__ float As[16][68];
    __shared__ float Wsh[16][68];
    int tid = threadIdx.x;
    int bm = blockIdx.y * 64;
    int bn = blockIdx.x * 64;
    int tx = tid & 15, ty = tid >> 4;
    float acc[4][4] = {};

    for (int k0 = 0; k0 < K; k0 += 16) {
        #pragma unroll
        for (int p = 0; p < 4; ++p) {
            int li = tid + p * 256;
            int m = li >> 4, k = li & 15;
            As[k][m] = A[(size_t)(bm + m) * lda + (k0 + k)];
            if (!wtrans) {
                Wsh[k][m] = W[(size_t)(bn + m) * K + (k0 + k)];
            } else {
                int kt = li >> 6, mt = li & 63;
                Wsh[kt][mt] = W[(size_t)(k0 + kt) * N + (bn + mt)];
            }
        }
        __syncthreads();
        #pragma unroll
        for (int kk = 0; kk < 16; ++kk) {
            const float4 av = *reinterpret_cast<const float4*>(&As[kk][ty * 4]);
            const float4 wv = *reinterpret_cast<const float4*>(&Wsh[kk][tx * 4]);
            float a[4] = {av.x, av.y, av.z, av.w};
            float wq[4] = {wv.x, wv.y, wv.z, wv.w};
            #pragma unroll
            for (int i = 0; i < 4; ++i)
                #pragma unroll
                for (int j = 0; j < 4; ++j)
                    acc[i][j] += a[i] * wq[j];
        }
        __syncthreads();
    }
    #pragma unroll
    for (int i = 0; i < 4; ++i)
        #pragma unroll
        for (int j = 0; j < 4; ++j)
            C[(size_t)(bm + ty * 4 + i) * ldc + bn + tx * 4 + j] = acc[i][j];
}

// --------------------------------------------- depthwise causal conv + SiLU
__global__ __launch_bounds__(256) void conv_silu_kernel(
    const float* __restrict__ xz, const float* __restrict__ w,
    const float* __restrict__ cb, float* __restrict__ u)
{
    int idx = blockIdx.x * 256 + threadIdx.x;     // R*D_INNER threads
    int d = idx & (D_INNER - 1);
    int r = idx >> 11;                            // chunk-local row
    int t = r & (SEQL - 1);
    int rb = r - t;
    float acc = cb[d];
    #pragma unroll
    for (int j = 0; j < D_CONVK; ++j) {
        int tt = t - (D_CONVK - 1) + j;
        if (tt >= 0)
            acc += w[d * D_CONVK + j] * xz[(size_t)(rb + tt) * (2 * D_INNER) + d];
    }
    float sig = 1.f / (1.f + __expf(-acc));
    u[(size_t)r * D_INNER + d] = acc * sig;
}

// -------------------------------------------- selective scan, segment pass 1
__global__ __launch_bounds__(256) void scan1_kernel(
    const float* __restrict__ u, const float* __restrict__ delta,
    const float* __restrict__ xdbl, const float* __restrict__ A_log,
    float* __restrict__ Pbuf, float* __restrict__ Hbuf)
{
    int tid = threadIdx.x;
    int s = tid & 15, cg = tid >> 4;
    int blk = blockIdx.x;                  // ((bb*SSEG)+g)*128 + dg
    int dg = blk & 127;
    int g  = (blk >> 7) & (SSEG - 1);
    int bb = blk >> 12;
    int d = dg * 16 + cg;
    const float Av = -expf(A_log[d * D_STATE + s]);
    float h = 0.f, P = 1.f;
    const size_t r0 = (size_t)bb * SEQL + (size_t)g * TSEG;

    for (int t0 = 0; t0 < TSEG; t0 += 8) {
        float dd[8], uu[8], Bv[8];
        #pragma unroll
        for (int j = 0; j < 8; ++j) dd[j] = delta[(r0 + t0 + j) * D_INNER + d];
        #pragma unroll
        for (int j = 0; j < 8; ++j) uu[j] = u[(r0 + t0 + j) * D_INNER + d];
        #pragma unroll
        for (int j = 0; j < 8; ++j) Bv[j] = xdbl[(r0 + t0 + j) * XDBL_N + DT_RANK + s];
        #pragma unroll
        for (int j = 0; j < 8; ++j) {
            float dA = __expf(dd[j] * Av);
            h = dA * h + (dd[j] * uu[j]) * Bv[j];
            P *= dA;
        }
    }
    size_t o = (((size_t)bb * SSEG + g) * D_INNER + d) * D_STATE + s;
    Pbuf[o] = P;
    Hbuf[o] = h;
}

// ------------------------------------- scan fixup: turn (P, h_end) into h_in
__global__ __launch_bounds__(256) void scan_fix_kernel(
    const float* __restrict__ Pbuf, float* __restrict__ Hbuf)
{
    int idx = blockIdx.x * 256 + threadIdx.x;   // CB*D_INNER*D_STATE threads
    int b  = idx >> 15;
    int ds = idx & 32767;
    float hin = 0.f;
    for (int g = 0; g < SSEG; ++g) {
        size_t o = ((size_t)(b * SSEG + g)) * (D_INNER * D_STATE) + ds;
        float he = Hbuf[o];
        float pp = Pbuf[o];
        Hbuf[o] = hin;
        hin = pp * hin + he;
    }
}

// -------------------------------------------- selective scan, segment pass 2
__global__ __launch_bounds__(256) void scan2_kernel(
    const float* __restrict__ u, const float* deltabuf /* aliases ybuf */,
    const float* __restrict__ xdbl, const float* __restrict__ Hin,
    const float* __restrict__ A_log, const float* __restrict__ Dsk,
    const float* __restrict__ xz, float* ybuf /* aliases deltabuf */)
{
    int tid = threadIdx.x;
    int s = tid & 15, cg = tid >> 4;
    int blk = blockIdx.x;
    int dg = blk & 127;
    int g  = (blk >> 7) & (SSEG - 1);
    int bb = blk >> 12;
    int d = dg * 16 + cg;
    const float Av = -expf(A_log[d * D_STATE + s]);
    const float Dv = Dsk[d];
    const size_t r0 = (size_t)bb * SEQL + (size_t)g * TSEG;
    float h = Hin[(((size_t)bb * SSEG + g) * D_INNER + d) * D_STATE + s];

    for (int t0 = 0; t0 < TSEG; t0 += 8) {
        float dd[8], uu[8], Bv[8], Cv[8], zz[8];
        #pragma unroll
        for (int j = 0; j < 8; ++j) dd[j] = deltabuf[(r0 + t0 + j) * D_INNER + d];
        #pragma unroll
        for (int j = 0; j < 8; ++j) uu[j] = u[(r0 + t0 + j) * D_INNER + d];
        #pragma unroll
        for (int j = 0; j < 8; ++j) Bv[j] = xdbl[(r0 + t0 + j) * XDBL_N + DT_RANK + s];
        #pragma unroll
        for (int j = 0; j < 8; ++j) Cv[j] = xdbl[(r0 + t0 + j) * XDBL_N + DT_RANK + D_STATE + s];
        if (s == 0) {
            #pragma unroll
            for (int j = 0; j < 8; ++j)
                zz[j] = xz[(r0 + t0 + j) * (2 * D_INNER) + D_INNER + d];
        }
        #pragma unroll
        for (int j = 0; j < 8; ++j) {
            float dA = __expf(dd[j] * Av);
            h = dA * h + (dd[j] * uu[j]) * Bv[j];
            float y = h * Cv[j];
            y += __shfl_xor(y, 1);
            y += __shfl_xor(y, 2);
            y += __shfl_xor(y, 4);
            y += __shfl_xor(y, 8);
            if (s == 0) {
                float zv = zz[j];
                float sig = 1.f / (1.f + __expf(-zv));
                ybuf[(r0 + t0 + j) * D_INNER + d] = (y + uu[j] * Dv) * (zv * sig);
            }
        }
    }
}

// ------------------------------------------------------------------- launch
extern "C" void kernel_launch(void* const* d_in, const int* in_sizes, int n_in,
                              void* d_out, int out_size, void* d_ws, size_t ws_size,
                              hipStream_t stream)
{
    const float* x      = (const float*)d_in[0];
    const float* gamma  = (const float*)d_in[1];
    const float* beta   = (const float*)d_in[2];
    const float* in_w[2]   = {(const float*)d_in[3],  (const float*)d_in[12]};
    const float* conv_w[2] = {(const float*)d_in[4],  (const float*)d_in[13]};
    const float* conv_b[2] = {(const float*)d_in[5],  (const float*)d_in[14]};
    const float* xp_w[2]   = {(const float*)d_in[6],  (const float*)d_in[15]};
    const float* dtp_w[2]  = {(const float*)d_in[7],  (const float*)d_in[16]};
    const float* dtp_b[2]  = {(const float*)d_in[8],  (const float*)d_in[17]};
    const float* A_log[2]  = {(const float*)d_in[9],  (const float*)d_in[18]};
    const float* Dsk[2]    = {(const float*)d_in[10], (const float*)d_in[19]};
    const float* out_w[2]  = {(const float*)d_in[11], (const float*)d_in[20]};
    const float* proj_w = (const float*)d_in[21];
    const float* proj_b = (const float*)d_in[22];
    float* out = (float*)d_out;

    // ---- pick batches-per-chunk so the workspace fits ws_size ----
    const size_t WF_FL = 2ull * 1024 * 2048;
    int CB = BATCH;
    while (CB > 1) {
        size_t R = (size_t)CB * SEQL;
        size_t fl = WF_FL + R * (1024 + 4096 + 2048 + 96 + 2048)
                  + 2ull * CB * SSEG * D_INNER * D_STATE;
        if (fl * sizeof(float) <= ws_size) break;
        CB >>= 1;
    }
    const int NC = BATCH / CB;
    const size_t R = (size_t)CB * SEQL;

    float* ws    = (float*)d_ws;
    float* Wf    = ws;                         // 2 * 1024*2048 (fused out@proj)
    float* xn    = Wf    + WF_FL;              // R*1024
    float* xz    = xn    + R * 1024;           // R*4096
    float* u     = xz    + R * 4096;           // R*2048
    float* xdbl  = u     + R * 2048;           // R*96
    float* delta = xdbl  + R * 96;             // R*2048 (scan2 writes y in place)
    float* Pbuf  = delta + R * 2048;           // CB*SSEG*2048*16
    float* Hbuf  = Pbuf  + (size_t)CB * SSEG * D_INNER * D_STATE;

    // ---- fuse output weights: Wf[dir][m, d] = sum proj_w[m, dir*1024+m1]*out_w[m1, d]
    {
        dim3 gf(2048 / 64, 1024 / 64);
        for (int dir = 0; dir < 2; ++dir)
            gemm_kernel<<<gf, 256, 0, stream>>>(proj_w + dir * 1024, 2 * D_MODEL,
                                                out_w[dir], 1024, 2048, 1,
                                                Wf + (size_t)dir * 1024 * 2048, 2048);
    }

    for (int c = 0; c < NC; ++c) {
        const size_t row0 = (size_t)c * R;

        ln_kernel<<<(int)R, 256, 0, stream>>>(x + row0 * D_MODEL, gamma, beta, xn);

        for (int dir = 0; dir < 2; ++dir) {
            // in-proj: xz = xn(flip?) @ in_w.T   M=R K=1024 N=4096
            dim3 g1(4096 / 128, (unsigned)(R / 128));
            mgemm_kernel<<<g1, 256, 0, stream>>>(xn, D_MODEL, dir,
                                                 in_w[dir], D_MODEL, 2 * D_INNER,
                                                 xz, 2 * D_INNER, 0, 0,
                                                 0, nullptr, nullptr);
            // depthwise conv + silu -> u
            conv_silu_kernel<<<(int)(R * D_INNER / 256), 256, 0, stream>>>(
                xz, conv_w[dir], conv_b[dir], u);
            // x_dbl = u @ xp_w.T   M=R K=2048 N=96
            dim3 g2(1, (unsigned)(R / 128));
            mgemm_kernel<<<g2, 256, 0, stream>>>(u, D_INNER, 0,
                                                 xp_w[dir], D_INNER, XDBL_N,
                                                 xdbl, XDBL_N, 0, 0,
                                                 0, nullptr, nullptr);
            // delta = softplus(dt @ dtp_w.T + dtp_b)  M=R K=64 N=2048
            dim3 g3(2048 / 128, (unsigned)(R / 128));
            mgemm_kernel<<<g3, 256, 0, stream>>>(xdbl, XDBL_N, 0,
                                                 dtp_w[dir], DT_RANK, D_INNER,
                                                 delta, D_INNER, 0, 0,
                                                 1, dtp_b[dir], nullptr);
            // segment-parallel selective scan (y gated, in place into delta)
            int nblk = CB * SSEG * 128;
            scan1_kernel<<<nblk, 256, 0, stream>>>(u, delta, xdbl, A_log[dir],
                                                   Pbuf, Hbuf);
            scan_fix_kernel<<<CB * 128, 256, 0, stream>>>(Pbuf, Hbuf);
            scan2_kernel<<<nblk, 256, 0, stream>>>(u, delta, xdbl, Hbuf,
                                                   A_log[dir], Dsk[dir], xz, delta);
            // fused out+proj: out(+)= y @ Wf[dir].T  M=R K=2048 N=1024
            dim3 g4(1024 / 128, (unsigned)(R / 128));
            mgemm_kernel<<<g4, 256, 0, stream>>>(delta, D_INNER, 0,
                                                 Wf + (size_t)dir * 1024 * 2048, D_INNER, D_MODEL,
                                                 out + row0 * D_MODEL, D_MODEL, 0, dir,
                                                 dir == 0 ? 2 : 3, proj_b,
                                                 x + row0 * D_MODEL);
        }
    }
}

// Round 5
// 2124.409 us; speedup vs baseline: 5.3587x; 1.3082x over previous
//
#include <hip/hip_runtime.h>
#include <cstdint>
#include <cstddef>

#define D_MODEL 1024
#define D_STATE 16
#define D_CONVK 4
#define D_INNER 2048
#define DT_RANK 64
#define XDBL_N  (DT_RANK + 2*D_STATE)   // 96
#define BATCH   4
#define SEQL    2048
#define SSEG    32                      // time segments for parallel scan
#define TSEG    (SEQL/SSEG)             // 64

typedef __attribute__((ext_vector_type(4))) float f32x4;
typedef __attribute__((ext_vector_type(8))) short s16x8;

__device__ __forceinline__ short f2bf(float f) {
    union { float f; unsigned u; } c; c.f = f;
    unsigned u = c.u;
    return (short)((u + 0x7fffu + ((u >> 16) & 1u)) >> 16);
}

// ------------------------------------------------- fp32 -> bf16 convert (x4)
__global__ __launch_bounds__(256) void cvt_kernel(
    const float* __restrict__ in, short* __restrict__ out)
{
    int i = blockIdx.x * 256 + threadIdx.x;
    float4 v = reinterpret_cast<const float4*>(in)[i];
    short4 o = { f2bf(v.x), f2bf(v.y), f2bf(v.z), f2bf(v.w) };
    reinterpret_cast<short4*>(out)[i] = o;
}

// ------------------------------- transpose + convert: out[c*R + r] = in[r*C + c]
__global__ __launch_bounds__(256) void tconv_kernel(
    const float* __restrict__ in, short* __restrict__ out, int R, int C)
{
    __shared__ float tile[32][33];
    int c0 = blockIdx.x * 32, r0 = blockIdx.y * 32;
    int tx = threadIdx.x & 31, ty = threadIdx.x >> 5;   // ty 0..7
    #pragma unroll
    for (int i = 0; i < 32; i += 8)
        tile[ty + i][tx] = in[(size_t)(r0 + ty + i) * C + c0 + tx];
    __syncthreads();
    #pragma unroll
    for (int i = 0; i < 32; i += 8)
        out[(size_t)(c0 + ty + i) * R + r0 + tx] = f2bf(tile[tx][ty + i]);
}

// --------------------------------------------------- LayerNorm (bf16 output)
__global__ __launch_bounds__(256) void ln_kernel(
    const float* __restrict__ x, const float* __restrict__ g,
    const float* __restrict__ be, short* __restrict__ xn)
{
    int r = blockIdx.x;
    int tid = threadIdx.x;                       // 256 threads, 4 floats each
    const float4 v = reinterpret_cast<const float4*>(x + (size_t)r * D_MODEL)[tid];
    float s  = v.x + v.y + v.z + v.w;
    float ss = v.x*v.x + v.y*v.y + v.z*v.z + v.w*v.w;
    #pragma unroll
    for (int o = 32; o >= 1; o >>= 1) { s += __shfl_down(s, o); ss += __shfl_down(ss, o); }
    __shared__ float sbuf[4], ssbuf[4];
    __shared__ float mu_s, rs_s;
    int wave = tid >> 6, lane = tid & 63;
    if (lane == 0) { sbuf[wave] = s; ssbuf[wave] = ss; }
    __syncthreads();
    if (tid == 0) {
        float S = 0.f, SS = 0.f;
        #pragma unroll
        for (int i = 0; i < 4; ++i) { S += sbuf[i]; SS += ssbuf[i]; }
        float mu = S * (1.0f / D_MODEL);
        float var = SS * (1.0f / D_MODEL) - mu * mu;
        mu_s = mu; rs_s = rsqrtf(var + 1e-5f);
    }
    __syncthreads();
    float mu = mu_s, rs = rs_s;
    const float4 gv = reinterpret_cast<const float4*>(g)[tid];
    const float4 bv = reinterpret_cast<const float4*>(be)[tid];
    short4 o = { f2bf((v.x - mu) * rs * gv.x + bv.x),
                 f2bf((v.y - mu) * rs * gv.y + bv.y),
                 f2bf((v.z - mu) * rs * gv.z + bv.z),
                 f2bf((v.w - mu) * rs * gv.w + bv.w) };
    reinterpret_cast<short4*>(xn + (size_t)r * D_MODEL)[tid] = o;
}

// --------------------------------------------------- bf16 MFMA GEMM (128x128)
// C[r, coloff+c] = sum_k A[r',k]*W[c,k]; A,W bf16 in memory, fp32 accumulate.
// A (M,K) lda; W (N,K); K%32==0, M%128==0, N arbitrary (guarded).
// epi: 0 fp32 | 1 softplus(acc+bias) fp32 | 2 acc+bias+resid fp32 | 3 fp32 +=
//    | 4 bf16 | 5 split: c<64 -> bf16 Cb[r*64+c], c>=64 -> fp32 Cf[r*32+c-64]
__global__ __launch_bounds__(256) void mgemm_kernel(
    const short* __restrict__ A, int lda, int flipA,
    const short* __restrict__ W, int K, int N,
    float* __restrict__ Cf, short* __restrict__ Cb, int ldc, int coloff, int flipC,
    int epi, const float* __restrict__ bias, const float* __restrict__ resid)
{
    __shared__ short As[128 * 32];
    __shared__ short Ws[128 * 32];
    const int t = threadIdx.x;
    const int bm = blockIdx.y * 128;
    const int bn = blockIdx.x * 128;

    // staging: thread t copies row srow, k-half shalf (16 bf16 = 2 granules)
    const int srow = t >> 1;
    const int shalf = t & 1;
    const int ssw = (srow >> 1) & 3;
    int gr = bm + srow;
    if (flipA) { int tt = gr & (SEQL - 1); gr = gr - tt + (SEQL - 1 - tt); }
    const short* Ap = A + (size_t)gr * lda + 16 * shalf;
    const int gn = bn + srow;
    const bool wvalid = (gn < N);
    const short* Wp = W + (size_t)(wvalid ? gn : 0) * K + 16 * shalf;
    const int ws0 = srow * 32 + (((2 * shalf + 0) ^ ssw) << 3);
    const int ws1 = srow * 32 + (((2 * shalf + 1) ^ ssw) << 3);

    // mfma: wave w owns 64x64 sub-tile at (wr, wc)
    const int w = t >> 6, l = t & 63;
    const int wr = w >> 1, wc = w & 1;
    const int lr = l & 15, ls = l >> 4;
    f32x4 acc[4][4] = {};

    int aoff[4], boff[4];
    #pragma unroll
    for (int i = 0; i < 4; ++i) {
        int ra = wr * 64 + i * 16 + lr;
        aoff[i] = ra * 32 + ((ls ^ ((ra >> 1) & 3)) << 3);
        int rb = wc * 64 + i * 16 + lr;
        boff[i] = rb * 32 + ((ls ^ ((rb >> 1) & 3)) << 3);
    }

    for (int k0 = 0; k0 < K; k0 += 32) {
        s16x8 a0 = *(const s16x8*)(Ap + k0);
        s16x8 a1 = *(const s16x8*)(Ap + k0 + 8);
        s16x8 w0 = {0,0,0,0,0,0,0,0}, w1 = {0,0,0,0,0,0,0,0};
        if (wvalid) {
            w0 = *(const s16x8*)(Wp + k0);
            w1 = *(const s16x8*)(Wp + k0 + 8);
        }
        *(s16x8*)&As[ws0] = a0;
        *(s16x8*)&As[ws1] = a1;
        *(s16x8*)&Ws[ws0] = w0;
        *(s16x8*)&Ws[ws1] = w1;
        __syncthreads();
        s16x8 af[4], bf[4];
        #pragma unroll
        for (int i = 0; i < 4; ++i) af[i] = *(const s16x8*)&As[aoff[i]];
        #pragma unroll
        for (int i = 0; i < 4; ++i) bf[i] = *(const s16x8*)&Ws[boff[i]];
        #pragma unroll
        for (int mi = 0; mi < 4; ++mi)
            #pragma unroll
            for (int ni = 0; ni < 4; ++ni)
                acc[mi][ni] = __builtin_amdgcn_mfma_f32_16x16x32_bf16(
                    af[mi], bf[ni], acc[mi][ni], 0, 0, 0);
        __syncthreads();
    }

    #pragma unroll
    for (int mi = 0; mi < 4; ++mi) {
        #pragma unroll
        for (int e = 0; e < 4; ++e) {
            int r = bm + wr * 64 + mi * 16 + ls * 4 + e;
            int rs = r;
            if (flipC) { int tt = r & (SEQL - 1); rs = r - tt + (SEQL - 1 - tt); }
            #pragma unroll
            for (int ni = 0; ni < 4; ++ni) {
                int c = bn + wc * 64 + ni * 16 + lr;
                if (c >= N) continue;
                float v = acc[mi][ni][e];
                if (epi == 5) {
                    if (c < DT_RANK) Cb[(size_t)r * DT_RANK + c] = f2bf(v);
                    else             Cf[(size_t)r * 32 + (c - DT_RANK)] = v;
                    continue;
                }
                if (epi == 1) {
                    v += bias[c];
                    v = (v > 20.f) ? v : log1pf(expf(v));
                } else if (epi == 2) {
                    v += bias[c] + resid[(size_t)r * N + c];
                }
                size_t o = (size_t)rs * ldc + coloff + c;
                if (epi == 3)      Cf[o] += v;
                else if (epi == 4) Cb[o] = f2bf(v);
                else               Cf[o] = v;
            }
        }
    }
}

// ------------------------- depthwise causal conv + SiLU (fp32 + bf16 outputs)
__global__ __launch_bounds__(256) void conv_silu_kernel(
    const float* __restrict__ xz, const float* __restrict__ w,
    const float* __restrict__ cb, float* __restrict__ u, short* __restrict__ ubf)
{
    int idx = blockIdx.x * 256 + threadIdx.x;     // R*D_INNER threads
    int d = idx & (D_INNER - 1);
    int r = idx >> 11;                            // chunk-local row
    int t = r & (SEQL - 1);
    int rb = r - t;
    float acc = cb[d];
    #pragma unroll
    for (int j = 0; j < D_CONVK; ++j) {
        int tt = t - (D_CONVK - 1) + j;
        if (tt >= 0)
            acc += w[d * D_CONVK + j] * xz[(size_t)(rb + tt) * (2 * D_INNER) + d];
    }
    float sig = 1.f / (1.f + __expf(-acc));
    float uv = acc * sig;
    u[(size_t)r * D_INNER + d] = uv;
    ubf[(size_t)r * D_INNER + d] = f2bf(uv);
}

// -------------------------------------------- selective scan, segment pass 1
__global__ __launch_bounds__(256) void scan1_kernel(
    const float* __restrict__ u, const float* __restrict__ delta,
    const float* __restrict__ BC, const float* __restrict__ A_log,
    float* __restrict__ Pbuf, float* __restrict__ Hbuf)
{
    int tid = threadIdx.x;
    int s = tid & 15, cg = tid >> 4;
    int blk = blockIdx.x;                  // ((bb*SSEG)+g)*128 + dg
    int dg = blk & 127;
    int g  = (blk >> 7) & (SSEG - 1);
    int bb = blk >> 12;
    int d = dg * 16 + cg;
    const float Av = -expf(A_log[d * D_STATE + s]);
    float h = 0.f, P = 1.f;
    const size_t r0 = (size_t)bb * SEQL + (size_t)g * TSEG;

    for (int t0 = 0; t0 < TSEG; t0 += 8) {
        float dd[8], uu[8], Bv[8];
        #pragma unroll
        for (int j = 0; j < 8; ++j) dd[j] = delta[(r0 + t0 + j) * D_INNER + d];
        #pragma unroll
        for (int j = 0; j < 8; ++j) uu[j] = u[(r0 + t0 + j) * D_INNER + d];
        #pragma unroll
        for (int j = 0; j < 8; ++j) Bv[j] = BC[(r0 + t0 + j) * 32 + s];
        #pragma unroll
        for (int j = 0; j < 8; ++j) {
            float dA = __expf(dd[j] * Av);
            h = dA * h + (dd[j] * uu[j]) * Bv[j];
            P *= dA;
        }
    }
    size_t o = (((size_t)bb * SSEG + g) * D_INNER + d) * D_STATE + s;
    Pbuf[o] = P;
    Hbuf[o] = h;
}

// ------------------------------------- scan fixup: turn (P, h_end) into h_in
__global__ __launch_bounds__(256) void scan_fix_kernel(
    const float* __restrict__ Pbuf, float* __restrict__ Hbuf)
{
    int idx = blockIdx.x * 256 + threadIdx.x;   // CB*D_INNER*D_STATE threads
    int b  = idx >> 15;
    int ds = idx & 32767;
    float hin = 0.f;
    for (int g = 0; g < SSEG; ++g) {
        size_t o = ((size_t)(b * SSEG + g)) * (D_INNER * D_STATE) + ds;
        float he = Hbuf[o];
        float pp = Pbuf[o];
        Hbuf[o] = hin;
        hin = pp * hin + he;
    }
}

// --------------------- selective scan, segment pass 2 (bf16 gated y output)
__global__ __launch_bounds__(256) void scan2_kernel(
    const float* __restrict__ u, const float* __restrict__ delta,
    const float* __restrict__ BC, const float* __restrict__ Hin,
    const float* __restrict__ A_log, const float* __restrict__ Dsk,
    const float* __restrict__ xz, short* __restrict__ ybf)
{
    int tid = threadIdx.x;
    int s = tid & 15, cg = tid >> 4;
    int blk = blockIdx.x;
    int dg = blk & 127;
    int g  = (blk >> 7) & (SSEG - 1);
    int bb = blk >> 12;
    int d = dg * 16 + cg;
    const float Av = -expf(A_log[d * D_STATE + s]);
    const float Dv = Dsk[d];
    const size_t r0 = (size_t)bb * SEQL + (size_t)g * TSEG;
    float h = Hin[(((size_t)bb * SSEG + g) * D_INNER + d) * D_STATE + s];

    for (int t0 = 0; t0 < TSEG; t0 += 8) {
        float dd[8], uu[8], Bv[8], Cv[8], zz[8];
        #pragma unroll
        for (int j = 0; j < 8; ++j) dd[j] = delta[(r0 + t0 + j) * D_INNER + d];
        #pragma unroll
        for (int j = 0; j < 8; ++j) uu[j] = u[(r0 + t0 + j) * D_INNER + d];
        #pragma unroll
        for (int j = 0; j < 8; ++j) Bv[j] = BC[(r0 + t0 + j) * 32 + s];
        #pragma unroll
        for (int j = 0; j < 8; ++j) Cv[j] = BC[(r0 + t0 + j) * 32 + 16 + s];
        if (s == 0) {
            #pragma unroll
            for (int j = 0; j < 8; ++j)
                zz[j] = xz[(r0 + t0 + j) * (2 * D_INNER) + D_INNER + d];
        }
        #pragma unroll
        for (int j = 0; j < 8; ++j) {
            float dA = __expf(dd[j] * Av);
            h = dA * h + (dd[j] * uu[j]) * Bv[j];
            float y = h * Cv[j];
            y += __shfl_xor(y, 1);
            y += __shfl_xor(y, 2);
            y += __shfl_xor(y, 4);
            y += __shfl_xor(y, 8);
            if (s == 0) {
                float zv = zz[j];
                float sig = 1.f / (1.f + __expf(-zv));
                ybf[(r0 + t0 + j) * D_INNER + d] = f2bf((y + uu[j] * Dv) * (zv * sig));
            }
        }
    }
}

// ------------------------------------------------------------------- launch
extern "C" void kernel_launch(void* const* d_in, const int* in_sizes, int n_in,
                              void* d_out, int out_size, void* d_ws, size_t ws_size,
                              hipStream_t stream)
{
    const float* x      = (const float*)d_in[0];
    const float* gamma  = (const float*)d_in[1];
    const float* beta   = (const float*)d_in[2];
    const float* in_w[2]   = {(const float*)d_in[3],  (const float*)d_in[12]};
    const float* conv_w[2] = {(const float*)d_in[4],  (const float*)d_in[13]};
    const float* conv_b[2] = {(const float*)d_in[5],  (const float*)d_in[14]};
    const float* xp_w[2]   = {(const float*)d_in[6],  (const float*)d_in[15]};
    const float* dtp_w[2]  = {(const float*)d_in[7],  (const float*)d_in[16]};
    const float* dtp_b[2]  = {(const float*)d_in[8],  (const float*)d_in[17]};
    const float* A_log[2]  = {(const float*)d_in[9],  (const float*)d_in[18]};
    const float* Dsk[2]    = {(const float*)d_in[10], (const float*)d_in[19]};
    const float* out_w[2]  = {(const float*)d_in[11], (const float*)d_in[20]};
    const float* proj_w = (const float*)d_in[21];
    const float* proj_b = (const float*)d_in[22];
    float* out = (float*)d_out;

    // ---- bf16 weight region ----
    short* wp = (short*)d_ws;
    short* in_bf[2]  = {wp, wp + 4096 * 1024};  wp += 2 * 4096 * 1024;
    short* xp_bf[2]  = {wp, wp + 96 * 2048};    wp += 2 * 96 * 2048;
    short* dtp_bf[2] = {wp, wp + 2048 * 64};    wp += 2 * 2048 * 64;
    short* proj_bf   = wp;                      wp += 1024 * 2048;
    short* outT_bf[2]= {wp, wp + 2048 * 1024};  wp += 2 * 2048 * 1024;
    short* Wf_bf[2]  = {wp, wp + 1024 * 2048};  wp += 2 * 1024 * 2048;
    const size_t fixed_bytes = (size_t)((char*)wp - (char*)d_ws);  // 39.06 MB, 16B-aligned

    // ---- pick batches-per-chunk so workspace fits ----
    // per chunk bytes: fp32 R*(4096+2048+2048+32+512+512)*4 + bf16 R*(1024+2048+64+2048)*2
    int CB = BATCH;
    while (CB > 1) {
        size_t R = (size_t)CB * SEQL;
        if (fixed_bytes + R * 47360ull <= ws_size) break;
        CB >>= 1;
    }
    const int NC = BATCH / CB;
    const size_t R = (size_t)CB * SEQL;

    float* fp    = (float*)wp;
    float* xz    = fp;            fp += R * 4096;
    float* u     = fp;            fp += R * 2048;
    float* delta = fp;            fp += R * 2048;
    float* BC    = fp;            fp += R * 32;
    float* Pbuf  = fp;            fp += R * 512;
    float* Hbuf  = fp;            fp += R * 512;
    short* sp    = (short*)fp;
    short* xn_bf = sp;            sp += R * 1024;
    short* u_bf  = sp;            sp += R * 2048;
    short* dt_bf = sp;            sp += R * 64;
    short* ybf   = sp;            sp += R * 2048;

    // ---- weight prep: convert / transpose-convert / MFMA fusion ----
    cvt_kernel<<<4096, 256, 0, stream>>>(in_w[0], in_bf[0]);
    cvt_kernel<<<4096, 256, 0, stream>>>(in_w[1], in_bf[1]);
    cvt_kernel<<<192, 256, 0, stream>>>(xp_w[0], xp_bf[0]);
    cvt_kernel<<<192, 256, 0, stream>>>(xp_w[1], xp_bf[1]);
    cvt_kernel<<<128, 256, 0, stream>>>(dtp_w[0], dtp_bf[0]);
    cvt_kernel<<<128, 256, 0, stream>>>(dtp_w[1], dtp_bf[1]);
    cvt_kernel<<<2048, 256, 0, stream>>>(proj_w, proj_bf);
    {
        dim3 gt(2048 / 32, 1024 / 32);
        tconv_kernel<<<gt, 256, 0, stream>>>(out_w[0], outT_bf[0], 1024, 2048);
        tconv_kernel<<<gt, 256, 0, stream>>>(out_w[1], outT_bf[1], 1024, 2048);
        // Wf[dir][m,d] = sum_m1 proj[m, dir*1024+m1] * out_w[m1, d]  (bf16 MFMA)
        dim3 gf(2048 / 128, 1024 / 128);
        for (int dir = 0; dir < 2; ++dir)
            mgemm_kernel<<<gf, 256, 0, stream>>>(proj_bf + dir * 1024, 2048, 0,
                                                 outT_bf[dir], 1024, 2048,
                                                 nullptr, Wf_bf[dir], 2048, 0, 0,
                                                 4, nullptr, nullptr);
    }

    for (int c = 0; c < NC; ++c) {
        const size_t row0 = (size_t)c * R;

        ln_kernel<<<(int)R, 256, 0, stream>>>(x + row0 * D_MODEL, gamma, beta, xn_bf);

        for (int dir = 0; dir < 2; ++dir) {
            // in-proj: xz = xn(flip?) @ in_w.T   M=R K=1024 N=4096
            dim3 g1(4096 / 128, (unsigned)(R / 128));
            mgemm_kernel<<<g1, 256, 0, stream>>>(xn_bf, D_MODEL, dir,
                                                 in_bf[dir], D_MODEL, 2 * D_INNER,
                                                 xz, nullptr, 2 * D_INNER, 0, 0,
                                                 0, nullptr, nullptr);
            // depthwise conv + silu -> u (fp32) + u_bf (bf16)
            conv_silu_kernel<<<(int)(R * D_INNER / 256), 256, 0, stream>>>(
                xz, conv_w[dir], conv_b[dir], u, u_bf);
            // x_dbl = u @ xp_w.T  M=R K=2048 N=96; split: dt->bf16, B|C->fp32 compact
            dim3 g2(1, (unsigned)(R / 128));
            mgemm_kernel<<<g2, 256, 0, stream>>>(u_bf, D_INNER, 0,
                                                 xp_bf[dir], D_INNER, XDBL_N,
                                                 BC, dt_bf, 0, 0, 0,
                                                 5, nullptr, nullptr);
            // delta = softplus(dt @ dtp_w.T + dtp_b)  M=R K=64 N=2048
            dim3 g3(2048 / 128, (unsigned)(R / 128));
            mgemm_kernel<<<g3, 256, 0, stream>>>(dt_bf, DT_RANK, 0,
                                                 dtp_bf[dir], DT_RANK, D_INNER,
                                                 delta, nullptr, D_INNER, 0, 0,
                                                 1, dtp_b[dir], nullptr);
            // segment-parallel selective scan -> ybf (bf16 gated y)
            int nblk = CB * SSEG * 128;
            scan1_kernel<<<nblk, 256, 0, stream>>>(u, delta, BC, A_log[dir],
                                                   Pbuf, Hbuf);
            scan_fix_kernel<<<CB * 128, 256, 0, stream>>>(Pbuf, Hbuf);
            scan2_kernel<<<nblk, 256, 0, stream>>>(u, delta, BC, Hbuf,
                                                   A_log[dir], Dsk[dir], xz, ybf);
            // fused out+proj: out(+)= y @ Wf[dir].T  M=R K=2048 N=1024
            dim3 g4(1024 / 128, (unsigned)(R / 128));
            mgemm_kernel<<<g4, 256, 0, stream>>>(ybf, D_INNER, 0,
                                                 Wf_bf[dir], D_INNER, D_MODEL,
                                                 out + row0 * D_MODEL, nullptr, D_MODEL, 0, dir,
                                                 dir == 0 ? 2 : 3, proj_b,
                                                 x + row0 * D_MODEL);
        }
    }
}

// Round 6
// 1738.826 us; speedup vs baseline: 6.5470x; 1.2217x over previous
//
#include <hip/hip_runtime.h>
#include <cstdint>
#include <cstddef>

#define D_MODEL 1024
#define D_STATE 16
#define D_CONVK 4
#define D_INNER 2048
#define DT_RANK 64
#define XDBL_N  (DT_RANK + 2*D_STATE)   // 96
#define BATCH   4
#define SEQL    2048
#define SSEG    64                      // time segments for parallel scan
#define TSEG    (SEQL/SSEG)             // 32

typedef __attribute__((ext_vector_type(4))) float f32x4;
typedef __attribute__((ext_vector_type(8))) short s16x8;

__device__ __forceinline__ short f2bf(float f) {
    union { float f; unsigned u; } c; c.f = f;
    unsigned u = c.u;
    return (short)((u + 0x7fffu + ((u >> 16) & 1u)) >> 16);
}

// ------------------------------------------------- fp32 -> bf16 convert (x4)
__global__ __launch_bounds__(256) void cvt_kernel(
    const float* __restrict__ in, short* __restrict__ out)
{
    int i = blockIdx.x * 256 + threadIdx.x;
    float4 v = reinterpret_cast<const float4*>(in)[i];
    short4 o = { f2bf(v.x), f2bf(v.y), f2bf(v.z), f2bf(v.w) };
    reinterpret_cast<short4*>(out)[i] = o;
}

// ------------------------------- transpose + convert: out[c*R + r] = in[r*C + c]
__global__ __launch_bounds__(256) void tconv_kernel(
    const float* __restrict__ in, short* __restrict__ out, int R, int C)
{
    __shared__ float tile[32][33];
    int c0 = blockIdx.x * 32, r0 = blockIdx.y * 32;
    int tx = threadIdx.x & 31, ty = threadIdx.x >> 5;   // ty 0..7
    #pragma unroll
    for (int i = 0; i < 32; i += 8)
        tile[ty + i][tx] = in[(size_t)(r0 + ty + i) * C + c0 + tx];
    __syncthreads();
    #pragma unroll
    for (int i = 0; i < 32; i += 8)
        out[(size_t)(c0 + ty + i) * R + r0 + tx] = f2bf(tile[tx][ty + i]);
}

// --------------------------------------------------- LayerNorm (bf16 output)
__global__ __launch_bounds__(256) void ln_kernel(
    const float* __restrict__ x, const float* __restrict__ g,
    const float* __restrict__ be, short* __restrict__ xn)
{
    int r = blockIdx.x;
    int tid = threadIdx.x;                       // 256 threads, 4 floats each
    const float4 v = reinterpret_cast<const float4*>(x + (size_t)r * D_MODEL)[tid];
    float s  = v.x + v.y + v.z + v.w;
    float ss = v.x*v.x + v.y*v.y + v.z*v.z + v.w*v.w;
    #pragma unroll
    for (int o = 32; o >= 1; o >>= 1) { s += __shfl_down(s, o); ss += __shfl_down(ss, o); }
    __shared__ float sbuf[4], ssbuf[4];
    __shared__ float mu_s, rs_s;
    int wave = tid >> 6, lane = tid & 63;
    if (lane == 0) { sbuf[wave] = s; ssbuf[wave] = ss; }
    __syncthreads();
    if (tid == 0) {
        float S = 0.f, SS = 0.f;
        #pragma unroll
        for (int i = 0; i < 4; ++i) { S += sbuf[i]; SS += ssbuf[i]; }
        float mu = S * (1.0f / D_MODEL);
        float var = SS * (1.0f / D_MODEL) - mu * mu;
        mu_s = mu; rs_s = rsqrtf(var + 1e-5f);
    }
    __syncthreads();
    float mu = mu_s, rs = rs_s;
    const float4 gv = reinterpret_cast<const float4*>(g)[tid];
    const float4 bv = reinterpret_cast<const float4*>(be)[tid];
    short4 o = { f2bf((v.x - mu) * rs * gv.x + bv.x),
                 f2bf((v.y - mu) * rs * gv.y + bv.y),
                 f2bf((v.z - mu) * rs * gv.z + bv.z),
                 f2bf((v.w - mu) * rs * gv.w + bv.w) };
    reinterpret_cast<short4*>(xn + (size_t)r * D_MODEL)[tid] = o;
}

// --------------------------------------------------- bf16 MFMA GEMM (128x128)
// C[r, coloff+c] = sum_k A[r',k]*W[c,k]; A,W bf16 in memory, fp32 accumulate.
// A (M,K) lda; W (N,K); K%32==0, M%128==0, N arbitrary (guarded).
// epi: 0 fp32 | 1 softplus(acc+bias) fp32 | 2 acc+bias+resid fp32 | 3 fp32 +=
//    | 4 bf16 | 5 split: c<64 -> bf16 Cb[r*64+c], c>=64 -> fp32 Cf[r*32+c-64]
__global__ __launch_bounds__(256) void mgemm_kernel(
    const short* __restrict__ A, int lda, int flipA,
    const short* __restrict__ W, int K, int N,
    float* __restrict__ Cf, short* __restrict__ Cb, int ldc, int coloff, int flipC,
    int epi, const float* __restrict__ bias, const float* __restrict__ resid)
{
    __shared__ short As[128 * 32];
    __shared__ short Ws[128 * 32];
    const int t = threadIdx.x;
    const int bm = blockIdx.y * 128;
    const int bn = blockIdx.x * 128;

    // staging: thread t copies row srow, k-half shalf (16 bf16 = 2 granules)
    const int srow = t >> 1;
    const int shalf = t & 1;
    const int ssw = (srow >> 1) & 3;
    int gr = bm + srow;
    if (flipA) { int tt = gr & (SEQL - 1); gr = gr - tt + (SEQL - 1 - tt); }
    const short* Ap = A + (size_t)gr * lda + 16 * shalf;
    const int gn = bn + srow;
    const bool wvalid = (gn < N);
    const short* Wp = W + (size_t)(wvalid ? gn : 0) * K + 16 * shalf;
    const int ws0 = srow * 32 + (((2 * shalf + 0) ^ ssw) << 3);
    const int ws1 = srow * 32 + (((2 * shalf + 1) ^ ssw) << 3);

    // mfma: wave w owns 64x64 sub-tile at (wr, wc)
    const int w = t >> 6, l = t & 63;
    const int wr = w >> 1, wc = w & 1;
    const int lr = l & 15, ls = l >> 4;
    f32x4 acc[4][4] = {};

    int aoff[4], boff[4];
    #pragma unroll
    for (int i = 0; i < 4; ++i) {
        int ra = wr * 64 + i * 16 + lr;
        aoff[i] = ra * 32 + ((ls ^ ((ra >> 1) & 3)) << 3);
        int rb = wc * 64 + i * 16 + lr;
        boff[i] = rb * 32 + ((ls ^ ((rb >> 1) & 3)) << 3);
    }

    for (int k0 = 0; k0 < K; k0 += 32) {
        s16x8 a0 = *(const s16x8*)(Ap + k0);
        s16x8 a1 = *(const s16x8*)(Ap + k0 + 8);
        s16x8 w0 = {0,0,0,0,0,0,0,0}, w1 = {0,0,0,0,0,0,0,0};
        if (wvalid) {
            w0 = *(const s16x8*)(Wp + k0);
            w1 = *(const s16x8*)(Wp + k0 + 8);
        }
        *(s16x8*)&As[ws0] = a0;
        *(s16x8*)&As[ws1] = a1;
        *(s16x8*)&Ws[ws0] = w0;
        *(s16x8*)&Ws[ws1] = w1;
        __syncthreads();
        s16x8 af[4], bf[4];
        #pragma unroll
        for (int i = 0; i < 4; ++i) af[i] = *(const s16x8*)&As[aoff[i]];
        #pragma unroll
        for (int i = 0; i < 4; ++i) bf[i] = *(const s16x8*)&Ws[boff[i]];
        #pragma unroll
        for (int mi = 0; mi < 4; ++mi)
            #pragma unroll
            for (int ni = 0; ni < 4; ++ni)
                acc[mi][ni] = __builtin_amdgcn_mfma_f32_16x16x32_bf16(
                    af[mi], bf[ni], acc[mi][ni], 0, 0, 0);
        __syncthreads();
    }

    #pragma unroll
    for (int mi = 0; mi < 4; ++mi) {
        #pragma unroll
        for (int e = 0; e < 4; ++e) {
            int r = bm + wr * 64 + mi * 16 + ls * 4 + e;
            int rs = r;
            if (flipC) { int tt = r & (SEQL - 1); rs = r - tt + (SEQL - 1 - tt); }
            #pragma unroll
            for (int ni = 0; ni < 4; ++ni) {
                int c = bn + wc * 64 + ni * 16 + lr;
                if (c >= N) continue;
                float v = acc[mi][ni][e];
                if (epi == 5) {
                    if (c < DT_RANK) Cb[(size_t)r * DT_RANK + c] = f2bf(v);
                    else             Cf[(size_t)r * 32 + (c - DT_RANK)] = v;
                    continue;
                }
                if (epi == 1) {
                    v += bias[c];
                    v = (v > 20.f) ? v : log1pf(expf(v));
                } else if (epi == 2) {
                    v += bias[c] + resid[(size_t)r * N + c];
                }
                size_t o = (size_t)rs * ldc + coloff + c;
                if (epi == 3)      Cf[o] += v;
                else if (epi == 4) Cb[o] = f2bf(v);
                else               Cf[o] = v;
            }
        }
    }
}

// ------------------------- depthwise causal conv + SiLU (fp32 + bf16 outputs)
__global__ __launch_bounds__(256) void conv_silu_kernel(
    const float* __restrict__ xz, const float* __restrict__ w,
    const float* __restrict__ cb, float* __restrict__ u, short* __restrict__ ubf)
{
    int idx = blockIdx.x * 256 + threadIdx.x;     // R*D_INNER threads
    int d = idx & (D_INNER - 1);
    int r = idx >> 11;                            // chunk-local row
    int t = r & (SEQL - 1);
    int rb = r - t;
    float acc = cb[d];
    #pragma unroll
    for (int j = 0; j < D_CONVK; ++j) {
        int tt = t - (D_CONVK - 1) + j;
        if (tt >= 0)
            acc += w[d * D_CONVK + j] * xz[(size_t)(rb + tt) * (2 * D_INNER) + d];
    }
    float sig = 1.f / (1.f + __expf(-acc));
    float uv = acc * sig;
    u[(size_t)r * D_INNER + d] = uv;
    ubf[(size_t)r * D_INNER + d] = f2bf(uv);
}

// ------------------- selective scan pass 1: lane-per-channel, states in regs
// P/H layout: [(bb*SSEG+g)*16 + s]*D_INNER + d  (coalesced per s)
__global__ __launch_bounds__(256) void scan1_kernel(
    const float* __restrict__ u, const float* __restrict__ delta,
    const float* __restrict__ BC, const float* __restrict__ A_log,
    float* __restrict__ Pbuf, float* __restrict__ Hbuf)
{
    int tid = threadIdx.x;
    int blk = blockIdx.x;                  // ((bb*SSEG)+g)*8 + dblk
    int dblk = blk & 7;
    int g  = (blk >> 3) & (SSEG - 1);
    int bb = blk >> 9;                     // 3 + 6 bits
    int d = dblk * 256 + tid;

    float Av[D_STATE], h[D_STATE], P[D_STATE];
    #pragma unroll
    for (int s = 0; s < D_STATE; ++s) {
        Av[s] = -expf(A_log[d * D_STATE + s]);
        h[s] = 0.f; P[s] = 1.f;
    }
    const size_t r0 = (size_t)bb * SEQL + (size_t)g * TSEG;

    for (int t0 = 0; t0 < TSEG; t0 += 4) {
        float dd[4], uu[4];
        #pragma unroll
        for (int j = 0; j < 4; ++j) dd[j] = delta[(r0 + t0 + j) * D_INNER + d];
        #pragma unroll
        for (int j = 0; j < 4; ++j) uu[j] = u[(r0 + t0 + j) * D_INNER + d];
        #pragma unroll
        for (int j = 0; j < 4; ++j) {
            const float* bc = BC + (r0 + t0 + j) * 32;   // wave-uniform -> s_load
            float du = dd[j] * uu[j];
            #pragma unroll
            for (int s = 0; s < D_STATE; ++s) {
                float dA = __expf(dd[j] * Av[s]);
                h[s] = dA * h[s] + du * bc[s];
                P[s] *= dA;
            }
        }
    }
    size_t ob = ((size_t)bb * SSEG + g) * (D_INNER * D_STATE);
    #pragma unroll
    for (int s = 0; s < D_STATE; ++s) {
        Pbuf[ob + s * D_INNER + d] = P[s];
        Hbuf[ob + s * D_INNER + d] = h[s];
    }
}

// ------------------------------------- scan fixup: turn (P, h_end) into h_in
__global__ __launch_bounds__(256) void scan_fix_kernel(
    const float* __restrict__ Pbuf, float* __restrict__ Hbuf)
{
    int idx = blockIdx.x * 256 + threadIdx.x;   // CB*D_INNER*D_STATE threads
    int b  = idx >> 15;
    int ds = idx & 32767;
    float hin = 0.f;
    for (int g = 0; g < SSEG; ++g) {
        size_t o = ((size_t)(b * SSEG + g)) * (D_INNER * D_STATE) + ds;
        float he = Hbuf[o];
        float pp = Pbuf[o];
        Hbuf[o] = hin;
        hin = pp * hin + he;
    }
}

// ------ selective scan pass 2: lane-per-channel; y, D-skip, silu(z) gate, bf16
__global__ __launch_bounds__(256) void scan2_kernel(
    const float* __restrict__ u, const float* __restrict__ delta,
    const float* __restrict__ BC, const float* __restrict__ Hin,
    const float* __restrict__ A_log, const float* __restrict__ Dsk,
    const float* __restrict__ xz, short* __restrict__ ybf)
{
    int tid = threadIdx.x;
    int blk = blockIdx.x;
    int dblk = blk & 7;
    int g  = (blk >> 3) & (SSEG - 1);
    int bb = blk >> 9;
    int d = dblk * 256 + tid;

    const size_t ob = ((size_t)bb * SSEG + g) * (D_INNER * D_STATE);
    float Av[D_STATE], h[D_STATE];
    #pragma unroll
    for (int s = 0; s < D_STATE; ++s) {
        Av[s] = -expf(A_log[d * D_STATE + s]);
        h[s] = Hin[ob + s * D_INNER + d];
    }
    const float Dv = Dsk[d];
    const size_t r0 = (size_t)bb * SEQL + (size_t)g * TSEG;

    for (int t0 = 0; t0 < TSEG; t0 += 4) {
        float dd[4], uu[4], zz[4];
        #pragma unroll
        for (int j = 0; j < 4; ++j) dd[j] = delta[(r0 + t0 + j) * D_INNER + d];
        #pragma unroll
        for (int j = 0; j < 4; ++j) uu[j] = u[(r0 + t0 + j) * D_INNER + d];
        #pragma unroll
        for (int j = 0; j < 4; ++j) zz[j] = xz[(r0 + t0 + j) * (2 * D_INNER) + D_INNER + d];
        #pragma unroll
        for (int j = 0; j < 4; ++j) {
            const float* bc = BC + (r0 + t0 + j) * 32;   // wave-uniform -> s_load
            float du = dd[j] * uu[j];
            float y = 0.f;
            #pragma unroll
            for (int s = 0; s < D_STATE; ++s) {
                float dA = __expf(dd[j] * Av[s]);
                h[s] = dA * h[s] + du * bc[s];
                y += h[s] * bc[16 + s];
            }
            y += uu[j] * Dv;
            float zv = zz[j];
            float sig = 1.f / (1.f + __expf(-zv));
            ybf[(r0 + t0 + j) * D_INNER + d] = f2bf(y * (zv * sig));
        }
    }
}

// ------------------------------------------------------------------- launch
extern "C" void kernel_launch(void* const* d_in, const int* in_sizes, int n_in,
                              void* d_out, int out_size, void* d_ws, size_t ws_size,
                              hipStream_t stream)
{
    const float* x      = (const float*)d_in[0];
    const float* gamma  = (const float*)d_in[1];
    const float* beta   = (const float*)d_in[2];
    const float* in_w[2]   = {(const float*)d_in[3],  (const float*)d_in[12]};
    const float* conv_w[2] = {(const float*)d_in[4],  (const float*)d_in[13]};
    const float* conv_b[2] = {(const float*)d_in[5],  (const float*)d_in[14]};
    const float* xp_w[2]   = {(const float*)d_in[6],  (const float*)d_in[15]};
    const float* dtp_w[2]  = {(const float*)d_in[7],  (const float*)d_in[16]};
    const float* dtp_b[2]  = {(const float*)d_in[8],  (const float*)d_in[17]};
    const float* A_log[2]  = {(const float*)d_in[9],  (const float*)d_in[18]};
    const float* Dsk[2]    = {(const float*)d_in[10], (const float*)d_in[19]};
    const float* out_w[2]  = {(const float*)d_in[11], (const float*)d_in[20]};
    const float* proj_w = (const float*)d_in[21];
    const float* proj_b = (const float*)d_in[22];
    float* out = (float*)d_out;

    // ---- bf16 weight region ----
    short* wp = (short*)d_ws;
    short* in_bf[2]  = {wp, wp + 4096 * 1024};  wp += 2 * 4096 * 1024;
    short* xp_bf[2]  = {wp, wp + 96 * 2048};    wp += 2 * 96 * 2048;
    short* dtp_bf[2] = {wp, wp + 2048 * 64};    wp += 2 * 2048 * 64;
    short* proj_bf   = wp;                      wp += 1024 * 2048;
    short* outT_bf[2]= {wp, wp + 2048 * 1024};  wp += 2 * 2048 * 1024;
    short* Wf_bf[2]  = {wp, wp + 1024 * 2048};  wp += 2 * 1024 * 2048;
    const size_t fixed_bytes = (size_t)((char*)wp - (char*)d_ws);  // 39.06 MB, 16B-aligned

    // ---- pick batches-per-chunk so workspace fits ----
    // per-row bytes: fp32 (4096+2048+2048+32+1024+1024)*4 + bf16 (1024+2048+64+2048)*2
    int CB = BATCH;
    while (CB > 1) {
        size_t R = (size_t)CB * SEQL;
        if (fixed_bytes + R * 51456ull <= ws_size) break;
        CB >>= 1;
    }
    const int NC = BATCH / CB;
    const size_t R = (size_t)CB * SEQL;

    float* fp    = (float*)wp;
    float* xz    = fp;            fp += R * 4096;
    float* u     = fp;            fp += R * 2048;
    float* delta = fp;            fp += R * 2048;
    float* BC    = fp;            fp += R * 32;
    float* Pbuf  = fp;            fp += R * 1024;   // CB*SSEG*2048*16
    float* Hbuf  = fp;            fp += R * 1024;
    short* sp    = (short*)fp;
    short* xn_bf = sp;            sp += R * 1024;
    short* u_bf  = sp;            sp += R * 2048;
    short* dt_bf = sp;            sp += R * 64;
    short* ybf   = sp;            sp += R * 2048;

    // ---- weight prep: convert / transpose-convert / MFMA fusion ----
    cvt_kernel<<<4096, 256, 0, stream>>>(in_w[0], in_bf[0]);
    cvt_kernel<<<4096, 256, 0, stream>>>(in_w[1], in_bf[1]);
    cvt_kernel<<<192, 256, 0, stream>>>(xp_w[0], xp_bf[0]);
    cvt_kernel<<<192, 256, 0, stream>>>(xp_w[1], xp_bf[1]);
    cvt_kernel<<<128, 256, 0, stream>>>(dtp_w[0], dtp_bf[0]);
    cvt_kernel<<<128, 256, 0, stream>>>(dtp_w[1], dtp_bf[1]);
    cvt_kernel<<<2048, 256, 0, stream>>>(proj_w, proj_bf);
    {
        dim3 gt(2048 / 32, 1024 / 32);
        tconv_kernel<<<gt, 256, 0, stream>>>(out_w[0], outT_bf[0], 1024, 2048);
        tconv_kernel<<<gt, 256, 0, stream>>>(out_w[1], outT_bf[1], 1024, 2048);
        // Wf[dir][m,d] = sum_m1 proj[m, dir*1024+m1] * out_w[m1, d]  (bf16 MFMA)
        dim3 gf(2048 / 128, 1024 / 128);
        for (int dir = 0; dir < 2; ++dir)
            mgemm_kernel<<<gf, 256, 0, stream>>>(proj_bf + dir * 1024, 2048, 0,
                                                 outT_bf[dir], 1024, 2048,
                                                 nullptr, Wf_bf[dir], 2048, 0, 0,
                                                 4, nullptr, nullptr);
    }

    for (int c = 0; c < NC; ++c) {
        const size_t row0 = (size_t)c * R;

        ln_kernel<<<(int)R, 256, 0, stream>>>(x + row0 * D_MODEL, gamma, beta, xn_bf);

        for (int dir = 0; dir < 2; ++dir) {
            // in-proj: xz = xn(flip?) @ in_w.T   M=R K=1024 N=4096
            dim3 g1(4096 / 128, (unsigned)(R / 128));
            mgemm_kernel<<<g1, 256, 0, stream>>>(xn_bf, D_MODEL, dir,
                                                 in_bf[dir], D_MODEL, 2 * D_INNER,
                                                 xz, nullptr, 2 * D_INNER, 0, 0,
                                                 0, nullptr, nullptr);
            // depthwise conv + silu -> u (fp32) + u_bf (bf16)
            conv_silu_kernel<<<(int)(R * D_INNER / 256), 256, 0, stream>>>(
                xz, conv_w[dir], conv_b[dir], u, u_bf);
            // x_dbl = u @ xp_w.T  M=R K=2048 N=96; split: dt->bf16, B|C->fp32 compact
            dim3 g2(1, (unsigned)(R / 128));
            mgemm_kernel<<<g2, 256, 0, stream>>>(u_bf, D_INNER, 0,
                                                 xp_bf[dir], D_INNER, XDBL_N,
                                                 BC, dt_bf, 0, 0, 0,
                                                 5, nullptr, nullptr);
            // delta = softplus(dt @ dtp_w.T + dtp_b)  M=R K=64 N=2048
            dim3 g3(2048 / 128, (unsigned)(R / 128));
            mgemm_kernel<<<g3, 256, 0, stream>>>(dt_bf, DT_RANK, 0,
                                                 dtp_bf[dir], DT_RANK, D_INNER,
                                                 delta, nullptr, D_INNER, 0, 0,
                                                 1, dtp_b[dir], nullptr);
            // segment-parallel selective scan -> ybf (bf16 gated y)
            int nblk = CB * SSEG * 8;
            scan1_kernel<<<nblk, 256, 0, stream>>>(u, delta, BC, A_log[dir],
                                                   Pbuf, Hbuf);
            scan_fix_kernel<<<CB * 128, 256, 0, stream>>>(Pbuf, Hbuf);
            scan2_kernel<<<nblk, 256, 0, stream>>>(u, delta, BC, Hbuf,
                                                   A_log[dir], Dsk[dir], xz, ybf);
            // fused out+proj: out(+)= y @ Wf[dir].T  M=R K=2048 N=1024
            dim3 g4(1024 / 128, (unsigned)(R / 128));
            mgemm_kernel<<<g4, 256, 0, stream>>>(ybf, D_INNER, 0,
                                                 Wf_bf[dir], D_INNER, D_MODEL,
                                                 out + row0 * D_MODEL, nullptr, D_MODEL, 0, dir,
                                                 dir == 0 ? 2 : 3, proj_b,
                                                 x + row0 * D_MODEL);
        }
    }
}

// Round 7
// 1668.640 us; speedup vs baseline: 6.8223x; 1.0421x over previous
//
#include <hip/hip_runtime.h>
#include <cstdint>
#include <cstddef>

#define D_MODEL 1024
#define D_STATE 16
#define D_CONVK 4
#define D_INNER 2048
#define DT_RANK 64
#define XDBL_N  (DT_RANK + 2*D_STATE)   // 96
#define BATCH   4
#define SEQL    2048
#define SSEG    64                      // time segments for parallel scan
#define TSEG    (SEQL/SSEG)             // 32

typedef __attribute__((ext_vector_type(4))) float f32x4;
typedef __attribute__((ext_vector_type(8))) short s16x8;

__device__ __forceinline__ short f2bf(float f) {
    union { float f; unsigned u; } c; c.f = f;
    unsigned u = c.u;
    return (short)((u + 0x7fffu + ((u >> 16) & 1u)) >> 16);
}
__device__ __forceinline__ float bf2f(short s) {
    union { unsigned u; float f; } c;
    c.u = ((unsigned)(unsigned short)s) << 16;
    return c.f;
}

#define GLDS(gp, lp) __builtin_amdgcn_global_load_lds( \
    (const __attribute__((address_space(1))) unsigned int*)(gp), \
    (__attribute__((address_space(3))) unsigned int*)(lp), 16, 0, 0)

// ------------------------------------------------- fp32 -> bf16 convert (x4)
__global__ __launch_bounds__(256) void cvt_kernel(
    const float* __restrict__ in, short* __restrict__ out)
{
    int i = blockIdx.x * 256 + threadIdx.x;
    float4 v = reinterpret_cast<const float4*>(in)[i];
    short4 o = { f2bf(v.x), f2bf(v.y), f2bf(v.z), f2bf(v.w) };
    reinterpret_cast<short4*>(out)[i] = o;
}

// ------------------------------- transpose + convert: out[c*R + r] = in[r*C + c]
__global__ __launch_bounds__(256) void tconv_kernel(
    const float* __restrict__ in, short* __restrict__ out, int R, int C)
{
    __shared__ float tile[32][33];
    int c0 = blockIdx.x * 32, r0 = blockIdx.y * 32;
    int tx = threadIdx.x & 31, ty = threadIdx.x >> 5;   // ty 0..7
    #pragma unroll
    for (int i = 0; i < 32; i += 8)
        tile[ty + i][tx] = in[(size_t)(r0 + ty + i) * C + c0 + tx];
    __syncthreads();
    #pragma unroll
    for (int i = 0; i < 32; i += 8)
        out[(size_t)(c0 + ty + i) * R + r0 + tx] = f2bf(tile[tx][ty + i]);
}

// --------------------------------------------------- LayerNorm (bf16 output)
__global__ __launch_bounds__(256) void ln_kernel(
    const float* __restrict__ x, const float* __restrict__ g,
    const float* __restrict__ be, short* __restrict__ xn)
{
    int r = blockIdx.x;
    int tid = threadIdx.x;                       // 256 threads, 4 floats each
    const float4 v = reinterpret_cast<const float4*>(x + (size_t)r * D_MODEL)[tid];
    float s  = v.x + v.y + v.z + v.w;
    float ss = v.x*v.x + v.y*v.y + v.z*v.z + v.w*v.w;
    #pragma unroll
    for (int o = 32; o >= 1; o >>= 1) { s += __shfl_down(s, o); ss += __shfl_down(ss, o); }
    __shared__ float sbuf[4], ssbuf[4];
    __shared__ float mu_s, rs_s;
    int wave = tid >> 6, lane = tid & 63;
    if (lane == 0) { sbuf[wave] = s; ssbuf[wave] = ss; }
    __syncthreads();
    if (tid == 0) {
        float S = 0.f, SS = 0.f;
        #pragma unroll
        for (int i = 0; i < 4; ++i) { S += sbuf[i]; SS += ssbuf[i]; }
        float mu = S * (1.0f / D_MODEL);
        float var = SS * (1.0f / D_MODEL) - mu * mu;
        mu_s = mu; rs_s = rsqrtf(var + 1e-5f);
    }
    __syncthreads();
    float mu = mu_s, rs = rs_s;
    const float4 gv = reinterpret_cast<const float4*>(g)[tid];
    const float4 bv = reinterpret_cast<const float4*>(be)[tid];
    short4 o = { f2bf((v.x - mu) * rs * gv.x + bv.x),
                 f2bf((v.y - mu) * rs * gv.y + bv.y),
                 f2bf((v.z - mu) * rs * gv.z + bv.z),
                 f2bf((v.w - mu) * rs * gv.w + bv.w) };
    reinterpret_cast<short4*>(xn + (size_t)r * D_MODEL)[tid] = o;
}

// --------------------------------------------------- bf16 MFMA GEMM (128x128)
// C[r, coloff+c] = sum_k A[r',k]*W[c,k]; bf16 in, fp32 acc.
// Staging via global_load_lds w=16: LDS linear, swizzle applied on SOURCE addr
// (involution: slot gs of row r sources global granule gs ^ ((r>>1)&3)), read
// side XORs identically. W rows clamped to N-1 (c>=N results discarded).
// epi: 1 softplus(acc+bias)->bf16 Cb | 2 acc+bias+resid->fp32 Cf | 3 Cf +=
//    | 4 bf16 Cb | 5 split: c<64 -> bf16 Cb[r*64+c], c in[64,96) -> fp32 Cf[r*32+c-64]
__global__ __launch_bounds__(256) void mgemm_kernel(
    const short* __restrict__ A, int lda, int flipA,
    const short* __restrict__ W, int K, int N,
    float* __restrict__ Cf, short* __restrict__ Cb, int ldc, int coloff, int flipC,
    int epi, const float* __restrict__ bias, const float* __restrict__ resid)
{
    __shared__ short As[128 * 32];
    __shared__ short Ws[128 * 32];
    const int t = threadIdx.x;
    const int bm = blockIdx.y * 128;
    const int bn = blockIdx.x * 128;
    const int w = t >> 6, l = t & 63;

    // ---- staging: wave w stages rows [w*32, w*32+32) of A and W tiles.
    // inst i covers 16 rows: slot = w*128 + i*64 + l; row = slot>>2; gs = slot&3
    const int row0 = w * 32 + (l >> 2);
    const int row1 = row0 + 16;
    const int gs = l & 3;
    const int g0 = (gs ^ ((row0 >> 1) & 3)) << 3;   // source granule offset (shorts)
    const int g1 = (gs ^ ((row1 >> 1) & 3)) << 3;
    int gra0 = bm + row0, gra1 = bm + row1;
    if (flipA) {
        int tt = gra0 & (SEQL - 1); gra0 = gra0 - tt + (SEQL - 1 - tt);
        tt = gra1 & (SEQL - 1); gra1 = gra1 - tt + (SEQL - 1 - tt);
    }
    const short* apt0 = A + (size_t)gra0 * lda + g0;
    const short* apt1 = A + (size_t)gra1 * lda + g1;
    int gn0 = bn + row0; if (gn0 >= N) gn0 = N - 1;
    int gn1 = bn + row1; if (gn1 >= N) gn1 = N - 1;
    const short* wpt0 = W + (size_t)gn0 * K + g0;
    const short* wpt1 = W + (size_t)gn1 * K + g1;
    short* lA0 = &As[w * 1024];
    short* lA1 = &As[w * 1024 + 512];
    short* lW0 = &Ws[w * 1024];
    short* lW1 = &Ws[w * 1024 + 512];

    // ---- mfma: wave w owns 64x64 sub-tile at (wr, wc)
    const int wr = w >> 1, wc = w & 1;
    const int lr = l & 15, ls = l >> 4;
    f32x4 acc[4][4] = {};

    int aoff[4], boff[4];
    #pragma unroll
    for (int i = 0; i < 4; ++i) {
        int ra = wr * 64 + i * 16 + lr;
        aoff[i] = ra * 32 + ((ls ^ ((ra >> 1) & 3)) << 3);
        int rb = wc * 64 + i * 16 + lr;
        boff[i] = rb * 32 + ((ls ^ ((rb >> 1) & 3)) << 3);
    }

    for (int k0 = 0; k0 < K; k0 += 32) {
        GLDS(apt0 + k0, lA0);
        GLDS(apt1 + k0, lA1);
        GLDS(wpt0 + k0, lW0);
        GLDS(wpt1 + k0, lW1);
        __syncthreads();
        s16x8 af[4], bf[4];
        #pragma unroll
        for (int i = 0; i < 4; ++i) af[i] = *(const s16x8*)&As[aoff[i]];
        #pragma unroll
        for (int i = 0; i < 4; ++i) bf[i] = *(const s16x8*)&Ws[boff[i]];
        #pragma unroll
        for (int mi = 0; mi < 4; ++mi)
            #pragma unroll
            for (int ni = 0; ni < 4; ++ni)
                acc[mi][ni] = __builtin_amdgcn_mfma_f32_16x16x32_bf16(
                    af[mi], bf[ni], acc[mi][ni], 0, 0, 0);
        __syncthreads();
    }

    #pragma unroll
    for (int mi = 0; mi < 4; ++mi) {
        #pragma unroll
        for (int e = 0; e < 4; ++e) {
            int r = bm + wr * 64 + mi * 16 + ls * 4 + e;
            int rs = r;
            if (flipC) { int tt = r & (SEQL - 1); rs = r - tt + (SEQL - 1 - tt); }
            #pragma unroll
            for (int ni = 0; ni < 4; ++ni) {
                int c = bn + wc * 64 + ni * 16 + lr;
                if (c >= N) continue;
                float v = acc[mi][ni][e];
                if (epi == 5) {
                    if (c < DT_RANK) Cb[(size_t)r * DT_RANK + c] = f2bf(v);
                    else             Cf[(size_t)r * 32 + (c - DT_RANK)] = v;
                    continue;
                }
                if (epi == 1) {
                    v += bias[c];
                    v = (v > 20.f) ? v : log1pf(expf(v));
                    Cb[(size_t)rs * ldc + c] = f2bf(v);
                    continue;
                }
                size_t o = (size_t)rs * ldc + coloff + c;
                if (epi == 2)      Cf[o] = v + bias[c] + resid[(size_t)r * N + c];
                else if (epi == 3) Cf[o] += v;
                else if (epi == 4) Cb[o] = f2bf(v);
                else               Cf[o] = v;
            }
        }
    }
}

// --------------- depthwise causal conv + SiLU (bf16 in, bf16 out)
__global__ __launch_bounds__(256) void conv_silu_kernel(
    const short* __restrict__ xz, const float* __restrict__ w,
    const float* __restrict__ cb, short* __restrict__ ubf)
{
    int idx = blockIdx.x * 256 + threadIdx.x;     // R*D_INNER threads
    int d = idx & (D_INNER - 1);
    int r = idx >> 11;                            // chunk-local row
    int t = r & (SEQL - 1);
    int rb = r - t;
    float acc = cb[d];
    #pragma unroll
    for (int j = 0; j < D_CONVK; ++j) {
        int tt = t - (D_CONVK - 1) + j;
        if (tt >= 0)
            acc += w[d * D_CONVK + j] * bf2f(xz[(size_t)(rb + tt) * (2 * D_INNER) + d]);
    }
    float sig = 1.f / (1.f + __expf(-acc));
    ubf[(size_t)r * D_INNER + d] = f2bf(acc * sig);
}

// ------------------- selective scan pass 1: lane-per-channel, states in regs
// P/H layout: [(bb*SSEG+g)*16 + s]*D_INNER + d  (coalesced per s)
__global__ __launch_bounds__(256) void scan1_kernel(
    const short* __restrict__ u, const short* __restrict__ delta,
    const float* __restrict__ BC, const float* __restrict__ A_log,
    float* __restrict__ Pbuf, float* __restrict__ Hbuf)
{
    int tid = threadIdx.x;
    int blk = blockIdx.x;                  // ((bb*SSEG)+g)*8 + dblk
    int dblk = blk & 7;
    int g  = (blk >> 3) & (SSEG - 1);
    int bb = blk >> 9;
    int d = dblk * 256 + tid;

    float Av[D_STATE], h[D_STATE], P[D_STATE];
    #pragma unroll
    for (int s = 0; s < D_STATE; ++s) {
        Av[s] = -expf(A_log[d * D_STATE + s]);
        h[s] = 0.f; P[s] = 1.f;
    }
    const size_t r0 = (size_t)bb * SEQL + (size_t)g * TSEG;

    for (int t0 = 0; t0 < TSEG; t0 += 4) {
        float dd[4], uu[4];
        #pragma unroll
        for (int j = 0; j < 4; ++j) dd[j] = bf2f(delta[(r0 + t0 + j) * D_INNER + d]);
        #pragma unroll
        for (int j = 0; j < 4; ++j) uu[j] = bf2f(u[(r0 + t0 + j) * D_INNER + d]);
        #pragma unroll
        for (int j = 0; j < 4; ++j) {
            const float* bc = BC + (r0 + t0 + j) * 32;   // wave-uniform -> s_load
            float du = dd[j] * uu[j];
            #pragma unroll
            for (int s = 0; s < D_STATE; ++s) {
                float dA = __expf(dd[j] * Av[s]);
                h[s] = dA * h[s] + du * bc[s];
                P[s] *= dA;
            }
        }
    }
    size_t ob = ((size_t)bb * SSEG + g) * (D_INNER * D_STATE);
    #pragma unroll
    for (int s = 0; s < D_STATE; ++s) {
        Pbuf[ob + s * D_INNER + d] = P[s];
        Hbuf[ob + s * D_INNER + d] = h[s];
    }
}

// ------------------------------------- scan fixup: turn (P, h_end) into h_in
__global__ __launch_bounds__(256) void scan_fix_kernel(
    const float* __restrict__ Pbuf, float* __restrict__ Hbuf)
{
    int idx = blockIdx.x * 256 + threadIdx.x;   // CB*D_INNER*D_STATE threads
    int b  = idx >> 15;
    int ds = idx & 32767;
    float hin = 0.f;
    for (int g = 0; g < SSEG; ++g) {
        size_t o = ((size_t)(b * SSEG + g)) * (D_INNER * D_STATE) + ds;
        float he = Hbuf[o];
        float pp = Pbuf[o];
        Hbuf[o] = hin;
        hin = pp * hin + he;
    }
}

// ------ selective scan pass 2: lane-per-channel; y, D-skip, silu(z) gate, bf16
__global__ __launch_bounds__(256) void scan2_kernel(
    const short* __restrict__ u, const short* __restrict__ delta,
    const float* __restrict__ BC, const float* __restrict__ Hin,
    const float* __restrict__ A_log, const float* __restrict__ Dsk,
    const short* __restrict__ xz, short* __restrict__ ybf)
{
    int tid = threadIdx.x;
    int blk = blockIdx.x;
    int dblk = blk & 7;
    int g  = (blk >> 3) & (SSEG - 1);
    int bb = blk >> 9;
    int d = dblk * 256 + tid;

    const size_t ob = ((size_t)bb * SSEG + g) * (D_INNER * D_STATE);
    float Av[D_STATE], h[D_STATE];
    #pragma unroll
    for (int s = 0; s < D_STATE; ++s) {
        Av[s] = -expf(A_log[d * D_STATE + s]);
        h[s] = Hin[ob + s * D_INNER + d];
    }
    const float Dv = Dsk[d];
    const size_t r0 = (size_t)bb * SEQL + (size_t)g * TSEG;

    for (int t0 = 0; t0 < TSEG; t0 += 4) {
        float dd[4], uu[4], zz[4];
        #pragma unroll
        for (int j = 0; j < 4; ++j) dd[j] = bf2f(delta[(r0 + t0 + j) * D_INNER + d]);
        #pragma unroll
        for (int j = 0; j < 4; ++j) uu[j] = bf2f(u[(r0 + t0 + j) * D_INNER + d]);
        #pragma unroll
        for (int j = 0; j < 4; ++j) zz[j] = bf2f(xz[(r0 + t0 + j) * (2 * D_INNER) + D_INNER + d]);
        #pragma unroll
        for (int j = 0; j < 4; ++j) {
            const float* bc = BC + (r0 + t0 + j) * 32;   // wave-uniform -> s_load
            float du = dd[j] * uu[j];
            float y = 0.f;
            #pragma unroll
            for (int s = 0; s < D_STATE; ++s) {
                float dA = __expf(dd[j] * Av[s]);
                h[s] = dA * h[s] + du * bc[s];
                y += h[s] * bc[16 + s];
            }
            y += uu[j] * Dv;
            float zv = zz[j];
            float sig = 1.f / (1.f + __expf(-zv));
            ybf[(r0 + t0 + j) * D_INNER + d] = f2bf(y * (zv * sig));
        }
    }
}

// ------------------------------------------------------------------- launch
extern "C" void kernel_launch(void* const* d_in, const int* in_sizes, int n_in,
                              void* d_out, int out_size, void* d_ws, size_t ws_size,
                              hipStream_t stream)
{
    const float* x      = (const float*)d_in[0];
    const float* gamma  = (const float*)d_in[1];
    const float* beta   = (const float*)d_in[2];
    const float* in_w[2]   = {(const float*)d_in[3],  (const float*)d_in[12]};
    const float* conv_w[2] = {(const float*)d_in[4],  (const float*)d_in[13]};
    const float* conv_b[2] = {(const float*)d_in[5],  (const float*)d_in[14]};
    const float* xp_w[2]   = {(const float*)d_in[6],  (const float*)d_in[15]};
    const float* dtp_w[2]  = {(const float*)d_in[7],  (const float*)d_in[16]};
    const float* dtp_b[2]  = {(const float*)d_in[8],  (const float*)d_in[17]};
    const float* A_log[2]  = {(const float*)d_in[9],  (const float*)d_in[18]};
    const float* Dsk[2]    = {(const float*)d_in[10], (const float*)d_in[19]};
    const float* out_w[2]  = {(const float*)d_in[11], (const float*)d_in[20]};
    const float* proj_w = (const float*)d_in[21];
    const float* proj_b = (const float*)d_in[22];
    float* out = (float*)d_out;

    // ---- bf16 weight region ----
    short* wp = (short*)d_ws;
    short* in_bf[2]  = {wp, wp + 4096 * 1024};  wp += 2 * 4096 * 1024;
    short* xp_bf[2]  = {wp, wp + 96 * 2048};    wp += 2 * 96 * 2048;
    short* dtp_bf[2] = {wp, wp + 2048 * 64};    wp += 2 * 2048 * 64;
    short* proj_bf   = wp;                      wp += 1024 * 2048;
    short* outT_bf[2]= {wp, wp + 2048 * 1024};  wp += 2 * 2048 * 1024;
    short* Wf_bf[2]  = {wp, wp + 1024 * 2048};  wp += 2 * 1024 * 2048;
    const size_t fixed_bytes = (size_t)((char*)wp - (char*)d_ws);  // ~39 MB

    // ---- pick batches-per-chunk so workspace fits ----
    // per-row bytes: fp32 (32 + 1024 + 1024)*4 + bf16 (1024+4096+2048+64+2048+2048)*2
    int CB = BATCH;
    while (CB > 1) {
        size_t R = (size_t)CB * SEQL;
        if (fixed_bytes + R * 30848ull <= ws_size) break;
        CB >>= 1;
    }
    const int NC = BATCH / CB;
    const size_t R = (size_t)CB * SEQL;

    float* fp    = (float*)wp;
    float* BC    = fp;            fp += R * 32;
    float* Pbuf  = fp;            fp += R * 1024;   // CB*SSEG*2048*16
    float* Hbuf  = fp;            fp += R * 1024;
    short* sp    = (short*)fp;
    short* xn_bf = sp;            sp += R * 1024;
    short* xz_bf = sp;            sp += R * 4096;
    short* u_bf  = sp;            sp += R * 2048;
    short* dt_bf = sp;            sp += R * 64;
    short* de_bf = sp;            sp += R * 2048;
    short* ybf   = sp;            sp += R * 2048;

    // ---- weight prep: convert / transpose-convert / MFMA fusion ----
    cvt_kernel<<<4096, 256, 0, stream>>>(in_w[0], in_bf[0]);
    cvt_kernel<<<4096, 256, 0, stream>>>(in_w[1], in_bf[1]);
    cvt_kernel<<<192, 256, 0, stream>>>(xp_w[0], xp_bf[0]);
    cvt_kernel<<<192, 256, 0, stream>>>(xp_w[1], xp_bf[1]);
    cvt_kernel<<<128, 256, 0, stream>>>(dtp_w[0], dtp_bf[0]);
    cvt_kernel<<<128, 256, 0, stream>>>(dtp_w[1], dtp_bf[1]);
    cvt_kernel<<<2048, 256, 0, stream>>>(proj_w, proj_bf);
    {
        dim3 gt(2048 / 32, 1024 / 32);
        tconv_kernel<<<gt, 256, 0, stream>>>(out_w[0], outT_bf[0], 1024, 2048);
        tconv_kernel<<<gt, 256, 0, stream>>>(out_w[1], outT_bf[1], 1024, 2048);
        // Wf[dir][m,d] = sum_m1 proj[m, dir*1024+m1] * out_w[m1, d]  (bf16 MFMA)
        dim3 gf(2048 / 128, 1024 / 128);
        for (int dir = 0; dir < 2; ++dir)
            mgemm_kernel<<<gf, 256, 0, stream>>>(proj_bf + dir * 1024, 2048, 0,
                                                 outT_bf[dir], 1024, 2048,
                                                 nullptr, Wf_bf[dir], 2048, 0, 0,
                                                 4, nullptr, nullptr);
    }

    for (int c = 0; c < NC; ++c) {
        const size_t row0 = (size_t)c * R;

        ln_kernel<<<(int)R, 256, 0, stream>>>(x + row0 * D_MODEL, gamma, beta, xn_bf);

        for (int dir = 0; dir < 2; ++dir) {
            // in-proj: xz = xn(flip?) @ in_w.T   M=R K=1024 N=4096, bf16 out
            dim3 g1(4096 / 128, (unsigned)(R / 128));
            mgemm_kernel<<<g1, 256, 0, stream>>>(xn_bf, D_MODEL, dir,
                                                 in_bf[dir], D_MODEL, 2 * D_INNER,
                                                 nullptr, xz_bf, 2 * D_INNER, 0, 0,
                                                 4, nullptr, nullptr);
            // depthwise conv + silu -> u_bf
            conv_silu_kernel<<<(int)(R * D_INNER / 256), 256, 0, stream>>>(
                xz_bf, conv_w[dir], conv_b[dir], u_bf);
            // x_dbl = u @ xp_w.T  M=R K=2048 N=96; split: dt->bf16, B|C->fp32 compact
            dim3 g2(1, (unsigned)(R / 128));
            mgemm_kernel<<<g2, 256, 0, stream>>>(u_bf, D_INNER, 0,
                                                 xp_bf[dir], D_INNER, XDBL_N,
                                                 BC, dt_bf, 0, 0, 0,
                                                 5, nullptr, nullptr);
            // delta = softplus(dt @ dtp_w.T + dtp_b) -> bf16  M=R K=64 N=2048
            dim3 g3(2048 / 128, (unsigned)(R / 128));
            mgemm_kernel<<<g3, 256, 0, stream>>>(dt_bf, DT_RANK, 0,
                                                 dtp_bf[dir], DT_RANK, D_INNER,
                                                 nullptr, de_bf, D_INNER, 0, 0,
                                                 1, dtp_b[dir], nullptr);
            // segment-parallel selective scan -> ybf (bf16 gated y)
            int nblk = CB * SSEG * 8;
            scan1_kernel<<<nblk, 256, 0, stream>>>(u_bf, de_bf, BC, A_log[dir],
                                                   Pbuf, Hbuf);
            scan_fix_kernel<<<CB * 128, 256, 0, stream>>>(Pbuf, Hbuf);
            scan2_kernel<<<nblk, 256, 0, stream>>>(u_bf, de_bf, BC, Hbuf,
                                                   A_log[dir], Dsk[dir], xz_bf, ybf);
            // fused out+proj: out(+)= y @ Wf[dir].T  M=R K=2048 N=1024
            dim3 g4(1024 / 128, (unsigned)(R / 128));
            mgemm_kernel<<<g4, 256, 0, stream>>>(ybf, D_INNER, 0,
                                                 Wf_bf[dir], D_INNER, D_MODEL,
                                                 out + row0 * D_MODEL, nullptr, D_MODEL, 0, dir,
                                                 dir == 0 ? 2 : 3, proj_b,
                                                 x + row0 * D_MODEL);
        }
    }
}

// Round 8
// 1218.746 us; speedup vs baseline: 9.3408x; 1.3691x over previous
//
#include <hip/hip_runtime.h>
#include <cstdint>
#include <cstddef>

#define D_MODEL 1024
#define D_STATE 16
#define D_CONVK 4
#define D_INNER 2048
#define DT_RANK 64
#define XDBL_N  (DT_RANK + 2*D_STATE)   // 96
#define BATCH   4
#define SEQL    2048
#define SSEG    32                      // time segments for parallel scan
#define TSEG    (SEQL/SSEG)             // 64

typedef __attribute__((ext_vector_type(4))) float f32x4;
typedef __attribute__((ext_vector_type(8))) short s16x8;

__device__ __forceinline__ short f2bf(float f) {
    union { float f; unsigned u; } c; c.f = f;
    unsigned u = c.u;
    return (short)((u + 0x7fffu + ((u >> 16) & 1u)) >> 16);
}
__device__ __forceinline__ float bf2f(short s) {
    union { unsigned u; float f; } c;
    c.u = ((unsigned)(unsigned short)s) << 16;
    return c.f;
}

#define GLDS(gp, lp) __builtin_amdgcn_global_load_lds( \
    (const __attribute__((address_space(1))) unsigned int*)(gp), \
    (__attribute__((address_space(3))) unsigned int*)(lp), 16, 0, 0)

// ------------------------------------------------- fp32 -> bf16 convert (x4)
__global__ __launch_bounds__(256) void cvt_kernel(
    const float* __restrict__ in, short* __restrict__ out)
{
    int i = blockIdx.x * 256 + threadIdx.x;
    float4 v = reinterpret_cast<const float4*>(in)[i];
    short4 o = { f2bf(v.x), f2bf(v.y), f2bf(v.z), f2bf(v.w) };
    reinterpret_cast<short4*>(out)[i] = o;
}

// ------------------------------- transpose + convert: out[c*R + r] = in[r*C + c]
__global__ __launch_bounds__(256) void tconv_kernel(
    const float* __restrict__ in, short* __restrict__ out, int R, int C)
{
    __shared__ float tile[32][33];
    int c0 = blockIdx.x * 32, r0 = blockIdx.y * 32;
    int tx = threadIdx.x & 31, ty = threadIdx.x >> 5;   // ty 0..7
    #pragma unroll
    for (int i = 0; i < 32; i += 8)
        tile[ty + i][tx] = in[(size_t)(r0 + ty + i) * C + c0 + tx];
    __syncthreads();
    #pragma unroll
    for (int i = 0; i < 32; i += 8)
        out[(size_t)(c0 + ty + i) * R + r0 + tx] = f2bf(tile[tx][ty + i]);
}

// --------------------------------------------------- LayerNorm (bf16 output)
__global__ __launch_bounds__(256) void ln_kernel(
    const float* __restrict__ x, const float* __restrict__ g,
    const float* __restrict__ be, short* __restrict__ xn)
{
    int r = blockIdx.x;
    int tid = threadIdx.x;                       // 256 threads, 4 floats each
    const float4 v = reinterpret_cast<const float4*>(x + (size_t)r * D_MODEL)[tid];
    float s  = v.x + v.y + v.z + v.w;
    float ss = v.x*v.x + v.y*v.y + v.z*v.z + v.w*v.w;
    #pragma unroll
    for (int o = 32; o >= 1; o >>= 1) { s += __shfl_down(s, o); ss += __shfl_down(ss, o); }
    __shared__ float sbuf[4], ssbuf[4];
    __shared__ float mu_s, rs_s;
    int wave = tid >> 6, lane = tid & 63;
    if (lane == 0) { sbuf[wave] = s; ssbuf[wave] = ss; }
    __syncthreads();
    if (tid == 0) {
        float S = 0.f, SS = 0.f;
        #pragma unroll
        for (int i = 0; i < 4; ++i) { S += sbuf[i]; SS += ssbuf[i]; }
        float mu = S * (1.0f / D_MODEL);
        float var = SS * (1.0f / D_MODEL) - mu * mu;
        mu_s = mu; rs_s = rsqrtf(var + 1e-5f);
    }
    __syncthreads();
    float mu = mu_s, rs = rs_s;
    const float4 gv = reinterpret_cast<const float4*>(g)[tid];
    const float4 bv = reinterpret_cast<const float4*>(be)[tid];
    short4 o = { f2bf((v.x - mu) * rs * gv.x + bv.x),
                 f2bf((v.y - mu) * rs * gv.y + bv.y),
                 f2bf((v.z - mu) * rs * gv.z + bv.z),
                 f2bf((v.w - mu) * rs * gv.w + bv.w) };
    reinterpret_cast<short4*>(xn + (size_t)r * D_MODEL)[tid] = o;
}

// ----------------------------------- bf16 MFMA GEMM (128x128, 2-phase dbuf)
// C[r, coloff+c] = sum_k A[r',k]*W[c,k]; bf16 in, fp32 acc.
// Staging via global_load_lds w=16 into double-buffered LDS; next K-step's
// loads issued right after the barrier so they fly under ds_read+MFMA (T3).
// LDS linear, swizzle on SOURCE addr (involution gs ^ ((row>>1)&3)), same XOR
// on read. W rows clamped to N-1 (c>=N results discarded).
// epi: 1 softplus(acc+bias)->bf16 Cb | 2 acc+bias+resid->fp32 Cf | 3 Cf +=
//    | 4 bf16 Cb | 5 split: c<64 -> bf16 Cb[r*64+c], c in[64,96) -> fp32 Cf[r*32+c-64]
__global__ __launch_bounds__(256) void mgemm_kernel(
    const short* __restrict__ A, int lda, int flipA,
    const short* __restrict__ W, int K, int N,
    float* __restrict__ Cf, short* __restrict__ Cb, int ldc, int coloff, int flipC,
    int epi, const float* __restrict__ bias, const float* __restrict__ resid)
{
    __shared__ short As[2][128 * 32];
    __shared__ short Ws[2][128 * 32];
    const int t = threadIdx.x;
    const int bm = blockIdx.y * 128;
    const int bn = blockIdx.x * 128;
    const int w = t >> 6, l = t & 63;

    // ---- staging: wave w stages rows [w*32, w*32+32) of A and W tiles.
    const int row0 = w * 32 + (l >> 2);
    const int row1 = row0 + 16;
    const int gs = l & 3;
    const int g0 = (gs ^ ((row0 >> 1) & 3)) << 3;   // source granule offset (shorts)
    const int g1 = (gs ^ ((row1 >> 1) & 3)) << 3;
    int gra0 = bm + row0, gra1 = bm + row1;
    if (flipA) {
        int tt = gra0 & (SEQL - 1); gra0 = gra0 - tt + (SEQL - 1 - tt);
        tt = gra1 & (SEQL - 1); gra1 = gra1 - tt + (SEQL - 1 - tt);
    }
    const short* apt0 = A + (size_t)gra0 * lda + g0;
    const short* apt1 = A + (size_t)gra1 * lda + g1;
    int gn0 = bn + row0; if (gn0 >= N) gn0 = N - 1;
    int gn1 = bn + row1; if (gn1 >= N) gn1 = N - 1;
    const short* wpt0 = W + (size_t)gn0 * K + g0;
    const short* wpt1 = W + (size_t)gn1 * K + g1;
    const int lofs0 = w * 1024;
    const int lofs1 = w * 1024 + 512;

    // ---- mfma: wave w owns 64x64 sub-tile at (wr, wc)
    const int wr = w >> 1, wc = w & 1;
    const int lr = l & 15, ls = l >> 4;
    f32x4 acc[4][4] = {};

    int aoff[4], boff[4];
    #pragma unroll
    for (int i = 0; i < 4; ++i) {
        int ra = wr * 64 + i * 16 + lr;
        aoff[i] = ra * 32 + ((ls ^ ((ra >> 1) & 3)) << 3);
        int rb = wc * 64 + i * 16 + lr;
        boff[i] = rb * 32 + ((ls ^ ((rb >> 1) & 3)) << 3);
    }

    const int nIter = K >> 5;
    // prologue: stage K-step 0 into buffer 0
    GLDS(apt0, &As[0][lofs0]);
    GLDS(apt1, &As[0][lofs1]);
    GLDS(wpt0, &Ws[0][lofs0]);
    GLDS(wpt1, &Ws[0][lofs1]);

    for (int it = 0; it < nIter; ++it) {
        const int cur = it & 1;
        __syncthreads();                    // drains vmcnt: buf[cur] ready
        if (it + 1 < nIter) {               // prefetch next K-step (flies under MFMA)
            const int k0 = (it + 1) << 5;
            GLDS(apt0 + k0, &As[cur ^ 1][lofs0]);
            GLDS(apt1 + k0, &As[cur ^ 1][lofs1]);
            GLDS(wpt0 + k0, &Ws[cur ^ 1][lofs0]);
            GLDS(wpt1 + k0, &Ws[cur ^ 1][lofs1]);
        }
        s16x8 af[4], bfr[4];
        #pragma unroll
        for (int i = 0; i < 4; ++i) af[i] = *(const s16x8*)&As[cur][aoff[i]];
        #pragma unroll
        for (int i = 0; i < 4; ++i) bfr[i] = *(const s16x8*)&Ws[cur][boff[i]];
        #pragma unroll
        for (int mi = 0; mi < 4; ++mi)
            #pragma unroll
            for (int ni = 0; ni < 4; ++ni)
                acc[mi][ni] = __builtin_amdgcn_mfma_f32_16x16x32_bf16(
                    af[mi], bfr[ni], acc[mi][ni], 0, 0, 0);
        // single barrier per K-step (top of loop); WAR safe: buf[cur^1] writes
        // only start after the barrier where all reads of it completed.
    }

    #pragma unroll
    for (int mi = 0; mi < 4; ++mi) {
        #pragma unroll
        for (int e = 0; e < 4; ++e) {
            int r = bm + wr * 64 + mi * 16 + ls * 4 + e;
            int rs = r;
            if (flipC) { int tt = r & (SEQL - 1); rs = r - tt + (SEQL - 1 - tt); }
            #pragma unroll
            for (int ni = 0; ni < 4; ++ni) {
                int c = bn + wc * 64 + ni * 16 + lr;
                if (c >= N) continue;
                float v = acc[mi][ni][e];
                if (epi == 5) {
                    if (c < DT_RANK) Cb[(size_t)r * DT_RANK + c] = f2bf(v);
                    else             Cf[(size_t)r * 32 + (c - DT_RANK)] = v;
                    continue;
                }
                if (epi == 1) {
                    v += bias[c];
                    v = (v > 20.f) ? v : log1pf(expf(v));
                    Cb[(size_t)rs * ldc + c] = f2bf(v);
                    continue;
                }
                size_t o = (size_t)rs * ldc + coloff + c;
                if (epi == 2)      Cf[o] = v + bias[c] + resid[(size_t)r * N + c];
                else if (epi == 3) Cf[o] += v;
                else if (epi == 4) Cb[o] = f2bf(v);
                else               Cf[o] = v;
            }
        }
    }
}

// --------------- depthwise causal conv + SiLU (bf16 in/out, 8 ch/thread)
__global__ __launch_bounds__(256) void conv_silu_kernel(
    const short* __restrict__ xz, const float* __restrict__ w,
    const float* __restrict__ cb, short* __restrict__ ubf)
{
    int idx = blockIdx.x * 256 + threadIdx.x;     // R*256 threads total
    int d8 = idx & 255;                           // channel-group of 8
    int r  = idx >> 8;                            // chunk-local row
    int t = r & (SEQL - 1);
    int rb = r - t;
    int d0 = d8 * 8;

    float4 wv[8];
    #pragma unroll
    for (int e = 0; e < 8; ++e) wv[e] = ((const float4*)w)[d0 + e];
    float4 c0 = ((const float4*)cb)[d8 * 2];
    float4 c1 = ((const float4*)cb)[d8 * 2 + 1];
    float acc[8] = { c0.x, c0.y, c0.z, c0.w, c1.x, c1.y, c1.z, c1.w };

    #pragma unroll
    for (int j = 0; j < D_CONVK; ++j) {
        int tt = t - (D_CONVK - 1) + j;
        if (tt < 0) continue;
        s16x8 v = *(const s16x8*)&xz[(size_t)(rb + tt) * (2 * D_INNER) + d0];
        #pragma unroll
        for (int e = 0; e < 8; ++e)
            acc[e] += (&wv[e].x)[j] * bf2f(v[e]);
    }
    s16x8 o;
    #pragma unroll
    for (int e = 0; e < 8; ++e) {
        float sig = 1.f / (1.f + __expf(-acc[e]));
        o[e] = f2bf(acc[e] * sig);
    }
    *(s16x8*)&ubf[(size_t)r * D_INNER + d0] = o;
}

// ------------------- selective scan pass 1: lane-per-channel, states in regs
// P/H layout: [(bb*SSEG+g)*16 + s]*D_INNER + d  (coalesced per s)
__global__ __launch_bounds__(256) void scan1_kernel(
    const short* __restrict__ u, const short* __restrict__ delta,
    const float* __restrict__ BC, const float* __restrict__ A_log,
    float* __restrict__ Pbuf, float* __restrict__ Hbuf)
{
    int tid = threadIdx.x;
    int blk = blockIdx.x;                  // ((bb*SSEG)+g)*8 + dblk
    int dblk = blk & 7;
    int g  = (blk >> 3) & (SSEG - 1);
    int bb = blk >> 8;
    int d = dblk * 256 + tid;

    float Av[D_STATE], h[D_STATE], P[D_STATE];
    #pragma unroll
    for (int s = 0; s < D_STATE; ++s) {
        Av[s] = -expf(A_log[d * D_STATE + s]);
        h[s] = 0.f; P[s] = 1.f;
    }
    const size_t r0 = (size_t)bb * SEQL + (size_t)g * TSEG;

    for (int t0 = 0; t0 < TSEG; t0 += 4) {
        float dd[4], uu[4];
        #pragma unroll
        for (int j = 0; j < 4; ++j) dd[j] = bf2f(delta[(r0 + t0 + j) * D_INNER + d]);
        #pragma unroll
        for (int j = 0; j < 4; ++j) uu[j] = bf2f(u[(r0 + t0 + j) * D_INNER + d]);
        #pragma unroll
        for (int j = 0; j < 4; ++j) {
            const float* bc = BC + (r0 + t0 + j) * 32;   // wave-uniform -> s_load
            float du = dd[j] * uu[j];
            #pragma unroll
            for (int s = 0; s < D_STATE; ++s) {
                float dA = __expf(dd[j] * Av[s]);
                h[s] = dA * h[s] + du * bc[s];
                P[s] *= dA;
            }
        }
    }
    size_t ob = ((size_t)bb * SSEG + g) * (D_INNER * D_STATE);
    #pragma unroll
    for (int s = 0; s < D_STATE; ++s) {
        Pbuf[ob + s * D_INNER + d] = P[s];
        Hbuf[ob + s * D_INNER + d] = h[s];
    }
}

// ------------------------------------- scan fixup: turn (P, h_end) into h_in
__global__ __launch_bounds__(256) void scan_fix_kernel(
    const float* __restrict__ Pbuf, float* __restrict__ Hbuf)
{
    int idx = blockIdx.x * 256 + threadIdx.x;   // CB*D_INNER*D_STATE threads
    int b  = idx >> 15;
    int ds = idx & 32767;
    float hin = 0.f;
    for (int g = 0; g < SSEG; ++g) {
        size_t o = ((size_t)(b * SSEG + g)) * (D_INNER * D_STATE) + ds;
        float he = Hbuf[o];
        float pp = Pbuf[o];
        Hbuf[o] = hin;
        hin = pp * hin + he;
    }
}

// ------ selective scan pass 2: lane-per-channel; y, D-skip, silu(z) gate.
// ybf may alias delta (same-thread read-before-write) -> no restrict on those.
__global__ __launch_bounds__(256) void scan2_kernel(
    const short* __restrict__ u, const short* delta,
    const float* __restrict__ BC, const float* __restrict__ Hin,
    const float* __restrict__ A_log, const float* __restrict__ Dsk,
    const short* __restrict__ xz, short* ybf)
{
    int tid = threadIdx.x;
    int blk = blockIdx.x;
    int dblk = blk & 7;
    int g  = (blk >> 3) & (SSEG - 1);
    int bb = blk >> 8;
    int d = dblk * 256 + tid;

    const size_t ob = ((size_t)bb * SSEG + g) * (D_INNER * D_STATE);
    float Av[D_STATE], h[D_STATE];
    #pragma unroll
    for (int s = 0; s < D_STATE; ++s) {
        Av[s] = -expf(A_log[d * D_STATE + s]);
        h[s] = Hin[ob + s * D_INNER + d];
    }
    const float Dv = Dsk[d];
    const size_t r0 = (size_t)bb * SEQL + (size_t)g * TSEG;

    for (int t0 = 0; t0 < TSEG; t0 += 4) {
        float dd[4], uu[4], zz[4];
        #pragma unroll
        for (int j = 0; j < 4; ++j) dd[j] = bf2f(delta[(r0 + t0 + j) * D_INNER + d]);
        #pragma unroll
        for (int j = 0; j < 4; ++j) uu[j] = bf2f(u[(r0 + t0 + j) * D_INNER + d]);
        #pragma unroll
        for (int j = 0; j < 4; ++j) zz[j] = bf2f(xz[(r0 + t0 + j) * (2 * D_INNER) + D_INNER + d]);
        #pragma unroll
        for (int j = 0; j < 4; ++j) {
            const float* bc = BC + (r0 + t0 + j) * 32;   // wave-uniform -> s_load
            float du = dd[j] * uu[j];
            float y = 0.f;
            #pragma unroll
            for (int s = 0; s < D_STATE; ++s) {
                float dA = __expf(dd[j] * Av[s]);
                h[s] = dA * h[s] + du * bc[s];
                y += h[s] * bc[16 + s];
            }
            y += uu[j] * Dv;
            float zv = zz[j];
            float sig = 1.f / (1.f + __expf(-zv));
            ybf[(r0 + t0 + j) * D_INNER + d] = f2bf(y * (zv * sig));
        }
    }
}

// ------------------------------------------------------------------- launch
extern "C" void kernel_launch(void* const* d_in, const int* in_sizes, int n_in,
                              void* d_out, int out_size, void* d_ws, size_t ws_size,
                              hipStream_t stream)
{
    const float* x      = (const float*)d_in[0];
    const float* gamma  = (const float*)d_in[1];
    const float* beta   = (const float*)d_in[2];
    const float* in_w[2]   = {(const float*)d_in[3],  (const float*)d_in[12]};
    const float* conv_w[2] = {(const float*)d_in[4],  (const float*)d_in[13]};
    const float* conv_b[2] = {(const float*)d_in[5],  (const float*)d_in[14]};
    const float* xp_w[2]   = {(const float*)d_in[6],  (const float*)d_in[15]};
    const float* dtp_w[2]  = {(const float*)d_in[7],  (const float*)d_in[16]};
    const float* dtp_b[2]  = {(const float*)d_in[8],  (const float*)d_in[17]};
    const float* A_log[2]  = {(const float*)d_in[9],  (const float*)d_in[18]};
    const float* Dsk[2]    = {(const float*)d_in[10], (const float*)d_in[19]};
    const float* out_w[2]  = {(const float*)d_in[11], (const float*)d_in[20]};
    const float* proj_w = (const float*)d_in[21];
    const float* proj_b = (const float*)d_in[22];
    float* out = (float*)d_out;

    // ---- bf16 weight region ----
    short* wp = (short*)d_ws;
    short* in_bf[2]  = {wp, wp + 4096 * 1024};  wp += 2 * 4096 * 1024;
    short* xp_bf[2]  = {wp, wp + 96 * 2048};    wp += 2 * 96 * 2048;
    short* dtp_bf[2] = {wp, wp + 2048 * 64};    wp += 2 * 2048 * 64;
    short* proj_bf   = wp;                      wp += 1024 * 2048;
    short* outT_bf[2]= {wp, wp + 2048 * 1024};  wp += 2 * 2048 * 1024;
    short* Wf_bf[2]  = {wp, wp + 1024 * 2048};  wp += 2 * 1024 * 2048;
    const size_t fixed_bytes = (size_t)((char*)wp - (char*)d_ws);  // ~39 MB

    // ---- pick batches-per-chunk so workspace fits ----
    // per-row bytes: fp32 (32+512+512)*4 + bf16 (1024+4096+2048+64+2048)*2 = 22784
    int CB = BATCH;
    while (CB > 1) {
        size_t R = (size_t)CB * SEQL;
        if (fixed_bytes + R * 22784ull <= ws_size) break;
        CB >>= 1;
    }
    const int NC = BATCH / CB;
    const size_t R = (size_t)CB * SEQL;

    float* fp    = (float*)wp;
    float* BC    = fp;            fp += R * 32;
    float* Pbuf  = fp;            fp += R * 512;    // CB*SSEG*2048*16
    float* Hbuf  = fp;            fp += R * 512;
    short* sp    = (short*)fp;
    short* xn_bf = sp;            sp += R * 1024;
    short* xz_bf = sp;            sp += R * 4096;
    short* u_bf  = sp;            sp += R * 2048;
    short* dt_bf = sp;            sp += R * 64;
    short* de_bf = sp;            sp += R * 2048;   // delta; scan2 writes y in place

    // ---- weight prep: convert / transpose-convert / MFMA fusion ----
    cvt_kernel<<<4096, 256, 0, stream>>>(in_w[0], in_bf[0]);
    cvt_kernel<<<4096, 256, 0, stream>>>(in_w[1], in_bf[1]);
    cvt_kernel<<<192, 256, 0, stream>>>(xp_w[0], xp_bf[0]);
    cvt_kernel<<<192, 256, 0, stream>>>(xp_w[1], xp_bf[1]);
    cvt_kernel<<<128, 256, 0, stream>>>(dtp_w[0], dtp_bf[0]);
    cvt_kernel<<<128, 256, 0, stream>>>(dtp_w[1], dtp_bf[1]);
    cvt_kernel<<<2048, 256, 0, stream>>>(proj_w, proj_bf);
    {
        dim3 gt(2048 / 32, 1024 / 32);
        tconv_kernel<<<gt, 256, 0, stream>>>(out_w[0], outT_bf[0], 1024, 2048);
        tconv_kernel<<<gt, 256, 0, stream>>>(out_w[1], outT_bf[1], 1024, 2048);
        // Wf[dir][m,d] = sum_m1 proj[m, dir*1024+m1] * out_w[m1, d]  (bf16 MFMA)
        dim3 gf(2048 / 128, 1024 / 128);
        for (int dir = 0; dir < 2; ++dir)
            mgemm_kernel<<<gf, 256, 0, stream>>>(proj_bf + dir * 1024, 2048, 0,
                                                 outT_bf[dir], 1024, 2048,
                                                 nullptr, Wf_bf[dir], 2048, 0, 0,
                                                 4, nullptr, nullptr);
    }

    for (int c = 0; c < NC; ++c) {
        const size_t row0 = (size_t)c * R;

        ln_kernel<<<(int)R, 256, 0, stream>>>(x + row0 * D_MODEL, gamma, beta, xn_bf);

        for (int dir = 0; dir < 2; ++dir) {
            // in-proj: xz = xn(flip?) @ in_w.T   M=R K=1024 N=4096, bf16 out
            dim3 g1(4096 / 128, (unsigned)(R / 128));
            mgemm_kernel<<<g1, 256, 0, stream>>>(xn_bf, D_MODEL, dir,
                                                 in_bf[dir], D_MODEL, 2 * D_INNER,
                                                 nullptr, xz_bf, 2 * D_INNER, 0, 0,
                                                 4, nullptr, nullptr);
            // depthwise conv + silu -> u_bf
            conv_silu_kernel<<<(int)R, 256, 0, stream>>>(
                xz_bf, conv_w[dir], conv_b[dir], u_bf);
            // x_dbl = u @ xp_w.T  M=R K=2048 N=96; split: dt->bf16, B|C->fp32 compact
            dim3 g2(1, (unsigned)(R / 128));
            mgemm_kernel<<<g2, 256, 0, stream>>>(u_bf, D_INNER, 0,
                                                 xp_bf[dir], D_INNER, XDBL_N,
                                                 BC, dt_bf, 0, 0, 0,
                                                 5, nullptr, nullptr);
            // delta = softplus(dt @ dtp_w.T + dtp_b) -> bf16  M=R K=64 N=2048
            dim3 g3(2048 / 128, (unsigned)(R / 128));
            mgemm_kernel<<<g3, 256, 0, stream>>>(dt_bf, DT_RANK, 0,
                                                 dtp_bf[dir], DT_RANK, D_INNER,
                                                 nullptr, de_bf, D_INNER, 0, 0,
                                                 1, dtp_b[dir], nullptr);
            // segment-parallel selective scan -> y in place over de_bf
            int nblk = CB * SSEG * 8;
            scan1_kernel<<<nblk, 256, 0, stream>>>(u_bf, de_bf, BC, A_log[dir],
                                                   Pbuf, Hbuf);
            scan_fix_kernel<<<CB * 128, 256, 0, stream>>>(Pbuf, Hbuf);
            scan2_kernel<<<nblk, 256, 0, stream>>>(u_bf, de_bf, BC, Hbuf,
                                                   A_log[dir], Dsk[dir], xz_bf, de_bf);
            // fused out+proj: out(+)= y @ Wf[dir].T  M=R K=2048 N=1024
            dim3 g4(1024 / 128, (unsigned)(R / 128));
            mgemm_kernel<<<g4, 256, 0, stream>>>(de_bf, D_INNER, 0,
                                                 Wf_bf[dir], D_INNER, D_MODEL,
                                                 out + row0 * D_MODEL, nullptr, D_MODEL, 0, dir,
                                                 dir == 0 ? 2 : 3, proj_b,
                                                 x + row0 * D_MODEL);
        }
    }
}